// Round 4
// baseline (570.473 us; speedup 1.0000x reference)
//
#include <hip/hip_runtime.h>
#include <math.h>

#define NN 50000
#define NE 800000
#define NB 64
#define IND 773
#define MPAD 50048   // 128-row-padded M

typedef __attribute__((ext_vector_type(8))) short short8_t;
typedef __attribute__((ext_vector_type(4))) float f32x4;

__device__ __forceinline__ float lrelu(float x) { return x > 0.f ? x : 0.2f * x; }
__device__ __forceinline__ short f2b(float f) {
    unsigned u = __float_as_uint(f);
    unsigned r = (u + 0x7fffu + ((u >> 16) & 1u)) >> 16;  // RNE
    return (short)r;
}
__device__ __forceinline__ float b2f(short s) {
    return __uint_as_float(((unsigned)(unsigned short)s) << 16);
}

#define GLOAD16(g, l) __builtin_amdgcn_global_load_lds(                         \
    (const __attribute__((address_space(1))) void*)(g),                         \
    (__attribute__((address_space(3))) void*)(l), 16, 0, 0)

// ---------------- bf16 MFMA GEMM, m97 structure ----------------
// A: [>=bm+128][K] bf16 (rows beyond M may be garbage; only C rows < M stored).
// Bt: [N][K] bf16 (pre-transposed). K multiple of 32, 16B-aligned rows.
// 128x128 tile, 4 waves (2x2), global_load_lds width-16 staging, linear LDS.
template<int RELU, int HASB>
__global__ __launch_bounds__(256) void gemm_lds(const short* __restrict__ A,
                                                const short* __restrict__ Bt,
                                                const float* __restrict__ bias,
                                                short* __restrict__ C,
                                                int M, int K, int N) {
    __shared__ short As[128 * 32];
    __shared__ short Bs[128 * 32];
    const int t = threadIdx.x;
    const int w = t >> 6, l = t & 63;
    const int l15 = l & 15, lh = l >> 4;
    const int bm = blockIdx.x * 128, bn = blockIdx.y * 128;
    const int wr = (w >> 1) * 64, wc = (w & 1) * 64;

    // staging: wave w covers tile rows [w*32, w*32+32); lane -> (row=l>>2, colb=(l&3)*8)
    const short* aG = A + (size_t)(bm + w * 32 + (l >> 2)) * K + (l & 3) * 8;
    const short* bG = Bt + (size_t)(bn + w * 32 + (l >> 2)) * K + (l & 3) * 8;
    short* aL = As + (w * 32) * 32;
    short* bL = Bs + (w * 32) * 32;

    f32x4 acc[4][4];
#pragma unroll
    for (int i = 0; i < 4; ++i)
#pragma unroll
        for (int j = 0; j < 4; ++j) acc[i][j] = (f32x4){0.f, 0.f, 0.f, 0.f};

    for (int k0 = 0; k0 < K; k0 += 32) {
        __syncthreads();
        GLOAD16(aG + k0, aL);
        GLOAD16(aG + (size_t)16 * K + k0, aL + 16 * 32);
        GLOAD16(bG + k0, bL);
        GLOAD16(bG + (size_t)16 * K + k0, bL + 16 * 32);
        __syncthreads();
        short8_t af[4], bfr[4];
#pragma unroll
        for (int mi = 0; mi < 4; ++mi)
            af[mi] = *(const short8_t*)&As[(wr + mi * 16 + l15) * 32 + lh * 8];
#pragma unroll
        for (int ni = 0; ni < 4; ++ni)
            bfr[ni] = *(const short8_t*)&Bs[(wc + ni * 16 + l15) * 32 + lh * 8];
#pragma unroll
        for (int mi = 0; mi < 4; ++mi)
#pragma unroll
            for (int ni = 0; ni < 4; ++ni)
                acc[mi][ni] = __builtin_amdgcn_mfma_f32_16x16x32_bf16(af[mi], bfr[ni], acc[mi][ni], 0, 0, 0);
    }

    // epilogue: C/D layout col=lane&15, row=(lane>>4)*4+r
#pragma unroll
    for (int mi = 0; mi < 4; ++mi) {
#pragma unroll
        for (int r = 0; r < 4; ++r) {
            int grow = bm + wr + mi * 16 + lh * 4 + r;
            if (grow >= M) continue;
#pragma unroll
            for (int ni = 0; ni < 4; ++ni) {
                int gcol = bn + wc + ni * 16 + l15;
                float v = acc[mi][ni][r];
                if (HASB) v += bias[gcol];
                if (RELU) v = fmaxf(v, 0.f);
                C[(size_t)grow * N + gcol] = f2b(v);
            }
        }
    }
}

// ---------------- x: fp32 [NN][773] -> bf16 [MPAD][800], zero K-pad ----------------
__global__ void k_cast_pad(const float* __restrict__ x, short* __restrict__ xb) {
    int idx = blockIdx.x * 256 + threadIdx.x;  // 8 cols per thread
    if (idx >= NN * 100) return;
    int row = idx / 100;
    int cb = (idx - row * 100) * 8;
    const float* xp = x + (size_t)row * IND + cb;
    short8_t o;
#pragma unroll
    for (int j = 0; j < 8; ++j)
        o[j] = (cb + j < IND) ? f2b(xp[j]) : (short)0;
    *(short8_t*)&xb[(size_t)row * 800 + cb] = o;
}

// ---------------- weight transpose+pad cast: Wt[n][k] = bf16(W[k][n]) ----------------
__global__ void k_wt(const float* __restrict__ W, short* __restrict__ Wt,
                     int K, int N, int Kp) {
    int idx = blockIdx.x * 256 + threadIdx.x;
    if (idx >= N * Kp) return;
    int n = idx / Kp, k = idx - n * Kp;
    Wt[idx] = (k < K) ? f2b(W[(size_t)k * N + n]) : (short)0;
}

// ---------------- attention dot products ----------------
template<int HD>
__global__ __launch_bounds__(256) void att_dots(const short* __restrict__ hW,
                                                const float* __restrict__ att_s,
                                                const float* __restrict__ att_d,
                                                float* __restrict__ a_s,
                                                float* __restrict__ a_d) {
    const int CPL = HD / 64;
    int node = blockIdx.x * 4 + (threadIdx.x >> 6);
    int lane = threadIdx.x & 63;
    if (node >= NN) return;
    const short* row = hW + (size_t)node * HD + lane * CPL;
    float s = 0.f, d = 0.f;
#pragma unroll
    for (int j = 0; j < CPL; ++j) {
        float v = b2f(row[j]);
        s += v * att_s[lane * CPL + j];
        d += v * att_d[lane * CPL + j];
    }
#pragma unroll
    for (int off = 1; off < 16; off <<= 1) {
        s += __shfl_xor(s, off);
        d += __shfl_xor(d, off);
    }
    int h = lane >> 4;
    if ((lane & 15) == 0) {
        a_s[node * 4 + h] = s;
        a_d[node * 4 + h] = d;
    }
}

// ---------------- CSR build ----------------
__global__ void k_hist(const int* __restrict__ ei, int* __restrict__ deg) {
    int e = blockIdx.x * 256 + threadIdx.x;
    if (e >= NE) return;
    atomicAdd(&deg[ei[NE + e]], 1);
}

__global__ __launch_bounds__(1024) void k_scan(const int* __restrict__ deg,
                                               int* __restrict__ row_ptr,
                                               int* __restrict__ cursor) {
    const int CH = (NN + 1023) / 1024;
    int t = threadIdx.x;
    int lo = t * CH, hi = lo + CH;
    if (hi > NN) hi = NN;
    int s = 0;
    for (int i = lo; i < hi; ++i) s += deg[i];
    __shared__ int sums[1024];
    sums[t] = s;
    __syncthreads();
    for (int off = 1; off < 1024; off <<= 1) {
        int v = (t >= off) ? sums[t - off] : 0;
        __syncthreads();
        sums[t] += v;
        __syncthreads();
    }
    int run = (t == 0) ? 0 : sums[t - 1];
    for (int i = lo; i < hi; ++i) {
        row_ptr[i] = run;
        cursor[i] = run;
        run += deg[i];
    }
    if (t == 1023) row_ptr[NN] = NE;
}

__global__ void k_scatter(const int* __restrict__ ei, int* __restrict__ cursor,
                          int* __restrict__ colidx) {
    int e = blockIdx.x * 256 + threadIdx.x;
    if (e >= NE) return;
    int s = ei[e], d = ei[NE + e];
    int pos = atomicAdd(&cursor[d], 1);
    colidx[pos] = s;
}

// ---------------- fused GAT aggregation (one wave per dst node), bf16 in/out ----------------
template<int HD>
__global__ __launch_bounds__(256) void gat_agg(const short* __restrict__ hW,
                                               const float* __restrict__ a_s,
                                               const float* __restrict__ a_d,
                                               const int* __restrict__ row_ptr,
                                               const int* __restrict__ colidx,
                                               const float* __restrict__ bias,
                                               short* __restrict__ outp) {
    const int CPL = HD / 64;
    int node = blockIdx.x * 4 + (threadIdx.x >> 6);
    int lane = threadIdx.x & 63;
    if (node >= NN) return;
    int h = lane >> 4;
    int start = row_ptr[node], end = row_ptr[node + 1];
    float adst = a_d[node * 4 + h];
    float eself = lrelu(a_s[node * 4 + h] + adst);

    float z = 1.f;
    float acc[CPL];
    {
        const short* row = hW + (size_t)node * HD + lane * CPL;
        if (CPL == 4) { short4 q = *(const short4*)row; acc[0]=b2f(q.x); acc[1]=b2f(q.y); acc[2]=b2f(q.z); acc[3]=b2f(q.w); }
        else          { short2 q = *(const short2*)row; acc[0]=b2f(q.x); acc[1]=b2f(q.y); }
    }
    int e = start;
    for (; e + 4 <= end; e += 4) {
        int s0 = colidx[e], s1 = colidx[e + 1], s2 = colidx[e + 2], s3 = colidx[e + 3];
        float x0 = a_s[s0 * 4 + h], x1 = a_s[s1 * 4 + h];
        float x2 = a_s[s2 * 4 + h], x3 = a_s[s3 * 4 + h];
        const short* r0 = hW + (size_t)s0 * HD + lane * CPL;
        const short* r1 = hW + (size_t)s1 * HD + lane * CPL;
        const short* r2 = hW + (size_t)s2 * HD + lane * CPL;
        const short* r3 = hW + (size_t)s3 * HD + lane * CPL;
        float v0[CPL], v1[CPL], v2[CPL], v3[CPL];
        if (CPL == 4) {
            short4 q0 = *(const short4*)r0, q1 = *(const short4*)r1;
            short4 q2 = *(const short4*)r2, q3 = *(const short4*)r3;
            v0[0]=b2f(q0.x); v0[1]=b2f(q0.y); v0[2]=b2f(q0.z); v0[3]=b2f(q0.w);
            v1[0]=b2f(q1.x); v1[1]=b2f(q1.y); v1[2]=b2f(q1.z); v1[3]=b2f(q1.w);
            v2[0]=b2f(q2.x); v2[1]=b2f(q2.y); v2[2]=b2f(q2.z); v2[3]=b2f(q2.w);
            v3[0]=b2f(q3.x); v3[1]=b2f(q3.y); v3[2]=b2f(q3.z); v3[3]=b2f(q3.w);
        } else {
            short2 q0 = *(const short2*)r0, q1 = *(const short2*)r1;
            short2 q2 = *(const short2*)r2, q3 = *(const short2*)r3;
            v0[0]=b2f(q0.x); v0[1]=b2f(q0.y);
            v1[0]=b2f(q1.x); v1[1]=b2f(q1.y);
            v2[0]=b2f(q2.x); v2[1]=b2f(q2.y);
            v3[0]=b2f(q3.x); v3[1]=b2f(q3.y);
        }
        float e0 = __expf(lrelu(x0 + adst) - eself);
        float e1 = __expf(lrelu(x1 + adst) - eself);
        float e2 = __expf(lrelu(x2 + adst) - eself);
        float e3 = __expf(lrelu(x3 + adst) - eself);
        z += (e0 + e1) + (e2 + e3);
#pragma unroll
        for (int j = 0; j < CPL; ++j)
            acc[j] += e0 * v0[j] + e1 * v1[j] + e2 * v2[j] + e3 * v3[j];
    }
    for (; e < end; ++e) {
        int s = colidx[e];
        float ex = __expf(lrelu(a_s[s * 4 + h] + adst) - eself);
        z += ex;
        const short* row = hW + (size_t)s * HD + lane * CPL;
        float v[CPL];
        if (CPL == 4) { short4 q = *(const short4*)row; v[0]=b2f(q.x); v[1]=b2f(q.y); v[2]=b2f(q.z); v[3]=b2f(q.w); }
        else          { short2 q = *(const short2*)row; v[0]=b2f(q.x); v[1]=b2f(q.y); }
#pragma unroll
        for (int j = 0; j < CPL; ++j) acc[j] += ex * v[j];
    }
    float inv = 1.f / z;
    short* orow = outp + (size_t)node * HD + lane * CPL;
#pragma unroll
    for (int j = 0; j < CPL; ++j)
        orow[j] = f2b(fmaxf(acc[j] * inv + bias[lane * CPL + j], 0.f));
}

// ---------------- pooling + classifier heads ----------------
__global__ __launch_bounds__(512) void pool_head(const short* __restrict__ h2,
                                                 const int* __restrict__ batch,
                                                 const float* __restrict__ W_cls,
                                                 const float* __restrict__ b_cls,
                                                 const float* __restrict__ W_conf,
                                                 const float* __restrict__ b_conf,
                                                 float* __restrict__ out) {
    int b = blockIdx.x;
    int t = threadIdx.x & 127;
    int g = threadIdx.x >> 7;
    int lo = 0, hi = NN;
    while (lo < hi) { int mid = (lo + hi) >> 1; if (batch[mid] < b) lo = mid + 1; else hi = mid; }
    int start = lo;
    lo = 0; hi = NN;
    while (lo < hi) { int mid = (lo + hi) >> 1; if (batch[mid] < b + 1) lo = mid + 1; else hi = mid; }
    int end = lo;

    float acc = 0.f;
    for (int n = start + g; n < end; n += 4) acc += b2f(h2[(size_t)n * 128 + t]);
    __shared__ float se[4][128];
    se[g][t] = acc;
    __syncthreads();
    if (g == 0) {
        float emb = (se[0][t] + se[1][t] + se[2][t] + se[3][t]) /
                    fmaxf((float)(end - start), 1.f);
        se[0][t] = emb;
    }
    __syncthreads();
    if (threadIdx.x == 0) {
        float v = b_cls[0];
        for (int c = 0; c < 128; ++c) v += se[0][c] * W_cls[c * 2 + 0];
        out[b * 2 + 0] = v;
    } else if (threadIdx.x == 1) {
        float v = b_cls[1];
        for (int c = 0; c < 128; ++c) v += se[0][c] * W_cls[c * 2 + 1];
        out[b * 2 + 1] = v;
    } else if (threadIdx.x == 2) {
        float v = b_conf[0];
        for (int c = 0; c < 128; ++c) v += se[0][c] * W_conf[c];
        out[128 + b] = 1.f / (1.f + expf(-v));
    }
}

extern "C" void kernel_launch(void* const* d_in, const int* in_sizes, int n_in,
                              void* d_out, int out_size, void* d_ws, size_t ws_size,
                              hipStream_t stream) {
    const float* x        = (const float*)d_in[0];
    const int*   ei       = (const int*)d_in[1];
    const int*   batch    = (const int*)d_in[2];
    const float* W_in     = (const float*)d_in[3];
    const float* b_in     = (const float*)d_in[4];
    const float* W1       = (const float*)d_in[5];
    const float* att_src1 = (const float*)d_in[6];
    const float* att_dst1 = (const float*)d_in[7];
    const float* b1       = (const float*)d_in[8];
    const float* W2       = (const float*)d_in[9];
    const float* att_src2 = (const float*)d_in[10];
    const float* att_dst2 = (const float*)d_in[11];
    const float* b2       = (const float*)d_in[12];
    const float* W_cls    = (const float*)d_in[13];
    const float* b_cls    = (const float*)d_in[14];
    const float* W_conf   = (const float*)d_in[15];
    const float* b_conf   = (const float*)d_in[16];
    float* out = (float*)d_out;

    char* ws = (char*)d_ws;
    // xb: [MPAD][800] bf16 = 80,076,800 B; after GEMM1 its region is reused:
    short* xb  = (short*)(ws + 0);
    short* hW1 = (short*)(ws + 0);            // [MPAD][256] 25,624,576
    short* h1  = (short*)(ws + 25624576);     // [MPAD][256]
    short* hW2 = (short*)(ws + 51249152);     // [MPAD][128] 12,812,288
    short* h2  = (short*)(ws + 64061440);     // [MPAD][128]
    short* h0  = (short*)(ws + 80076800);     // [MPAD][256]
    size_t base = 105701376;
    short* Wt_in = (short*)(ws + base);               // [256][800]
    short* Wt1   = (short*)(ws + base + 409600);      // [256][256]
    short* Wt2   = (short*)(ws + base + 540672);      // [128][256]
    float* a_s1  = (float*)(ws + base + 606208);      // [50000][4] (reused for layer 2)
    float* a_d1  = (float*)(ws + base + 1406208);
    int*   deg    = (int*)(ws + base + 2206208);
    int*   rowp   = (int*)(ws + base + 2406208);
    int*   cursor = (int*)(ws + base + 2606272);
    int*   colidx = (int*)(ws + base + 2806272);      // [800000]

    // casts
    k_wt<<<(256 * 800 + 255) / 256, 256, 0, stream>>>(W_in, Wt_in, IND, 256, 800);
    k_wt<<<(256 * 256 + 255) / 256, 256, 0, stream>>>(W1, Wt1, 256, 256, 256);
    k_wt<<<(128 * 256 + 255) / 256, 256, 0, stream>>>(W2, Wt2, 256, 128, 256);
    k_cast_pad<<<(NN * 100 + 255) / 256, 256, 0, stream>>>(x, xb);

    // CSR build
    hipMemsetAsync(deg, 0, NN * sizeof(int), stream);
    k_hist<<<NE / 256, 256, 0, stream>>>(ei, deg);
    k_scan<<<1, 1024, 0, stream>>>(deg, rowp, cursor);
    k_scatter<<<NE / 256, 256, 0, stream>>>(ei, cursor, colidx);

    // h0 = relu(xb @ W_in^T' + b_in)
    gemm_lds<1, 1><<<dim3(391, 2), 256, 0, stream>>>(xb, Wt_in, b_in, h0, NN, 800, 256);
    // hW1 = h0 @ W1   (overwrites xb region — xb dead)
    gemm_lds<0, 0><<<dim3(391, 2), 256, 0, stream>>>(h0, Wt1, nullptr, hW1, NN, 256, 256);
    att_dots<256><<<12500, 256, 0, stream>>>(hW1, att_src1, att_dst1, a_s1, a_d1);
    gat_agg<256><<<12500, 256, 0, stream>>>(hW1, a_s1, a_d1, rowp, colidx, b1, h1);
    // hW2 = h1 @ W2
    gemm_lds<0, 0><<<dim3(391, 1), 256, 0, stream>>>(h1, Wt2, nullptr, hW2, NN, 256, 128);
    att_dots<128><<<12500, 256, 0, stream>>>(hW2, att_src2, att_dst2, a_s1, a_d1);
    gat_agg<128><<<12500, 256, 0, stream>>>(hW2, a_s1, a_d1, rowp, colidx, b2, h2);
    pool_head<<<NB, 512, 0, stream>>>(h2, batch, W_cls, b_cls, W_conf, b_conf, out);
}

// Round 5
// 427.717 us; speedup vs baseline: 1.3338x; 1.3338x over previous
//
#include <hip/hip_runtime.h>
#include <math.h>

#define NN 50000
#define NE 800000
#define NB 64
#define IND 773
#define MPAD 50048   // 128-row-padded M
#define SCAN_B 196   // ceil(NN/256)

typedef __attribute__((ext_vector_type(8))) short short8_t;
typedef __attribute__((ext_vector_type(4))) float f32x4;

__device__ __forceinline__ float lrelu(float x) { return x > 0.f ? x : 0.2f * x; }
__device__ __forceinline__ short f2b(float f) {
    unsigned u = __float_as_uint(f);
    unsigned r = (u + 0x7fffu + ((u >> 16) & 1u)) >> 16;  // RNE
    return (short)r;
}
__device__ __forceinline__ float b2f(short s) {
    return __uint_as_float(((unsigned)(unsigned short)s) << 16);
}

#define GLOAD16(g, l) __builtin_amdgcn_global_load_lds(                         \
    (const __attribute__((address_space(1))) void*)(g),                         \
    (__attribute__((address_space(3))) void*)(l), 16, 0, 0)

// ---------------- bf16 MFMA GEMM, m97 structure ----------------
template<int RELU, int HASB>
__global__ __launch_bounds__(256) void gemm_lds(const short* __restrict__ A,
                                                const short* __restrict__ Bt,
                                                const float* __restrict__ bias,
                                                short* __restrict__ C,
                                                int M, int K, int N) {
    __shared__ short As[128 * 32];
    __shared__ short Bs[128 * 32];
    const int t = threadIdx.x;
    const int w = t >> 6, l = t & 63;
    const int l15 = l & 15, lh = l >> 4;
    const int bm = blockIdx.x * 128, bn = blockIdx.y * 128;
    const int wr = (w >> 1) * 64, wc = (w & 1) * 64;

    const short* aG = A + (size_t)(bm + w * 32 + (l >> 2)) * K + (l & 3) * 8;
    const short* bG = Bt + (size_t)(bn + w * 32 + (l >> 2)) * K + (l & 3) * 8;
    short* aL = As + (w * 32) * 32;
    short* bL = Bs + (w * 32) * 32;

    f32x4 acc[4][4];
#pragma unroll
    for (int i = 0; i < 4; ++i)
#pragma unroll
        for (int j = 0; j < 4; ++j) acc[i][j] = (f32x4){0.f, 0.f, 0.f, 0.f};

    for (int k0 = 0; k0 < K; k0 += 32) {
        __syncthreads();
        GLOAD16(aG + k0, aL);
        GLOAD16(aG + (size_t)16 * K + k0, aL + 16 * 32);
        GLOAD16(bG + k0, bL);
        GLOAD16(bG + (size_t)16 * K + k0, bL + 16 * 32);
        __syncthreads();
        short8_t af[4], bfr[4];
#pragma unroll
        for (int mi = 0; mi < 4; ++mi)
            af[mi] = *(const short8_t*)&As[(wr + mi * 16 + l15) * 32 + lh * 8];
#pragma unroll
        for (int ni = 0; ni < 4; ++ni)
            bfr[ni] = *(const short8_t*)&Bs[(wc + ni * 16 + l15) * 32 + lh * 8];
#pragma unroll
        for (int mi = 0; mi < 4; ++mi)
#pragma unroll
            for (int ni = 0; ni < 4; ++ni)
                acc[mi][ni] = __builtin_amdgcn_mfma_f32_16x16x32_bf16(af[mi], bfr[ni], acc[mi][ni], 0, 0, 0);
    }

#pragma unroll
    for (int mi = 0; mi < 4; ++mi) {
#pragma unroll
        for (int r = 0; r < 4; ++r) {
            int grow = bm + wr + mi * 16 + lh * 4 + r;
            if (grow >= M) continue;
#pragma unroll
            for (int ni = 0; ni < 4; ++ni) {
                int gcol = bn + wc + ni * 16 + l15;
                float v = acc[mi][ni][r];
                if (HASB) v += bias[gcol];
                if (RELU) v = fmaxf(v, 0.f);
                C[(size_t)grow * N + gcol] = f2b(v);
            }
        }
    }
}

// ---------------- x: fp32 [NN][773] -> bf16 [MPAD][800], branchless 16 cols/thread ----------------
__global__ __launch_bounds__(256) void k_cast_pad(const float* __restrict__ x,
                                                  short* __restrict__ xb) {
    int idx = blockIdx.x * 256 + threadIdx.x;  // 16 cols per thread
    if (idx >= NN * 50) return;
    int row = idx / 50;
    int c16 = idx - row * 50;
    int cb = c16 * 16;
    const float* xp = x + (size_t)row * IND + cb;
    short o[16];
    if (c16 < 48) {          // cb <= 752: all 16 in-range, unchecked
        float v[16];
#pragma unroll
        for (int j = 0; j < 16; ++j) v[j] = xp[j];
#pragma unroll
        for (int j = 0; j < 16; ++j) o[j] = f2b(v[j]);
    } else if (c16 == 48) {  // cb = 768: 5 valid
#pragma unroll
        for (int j = 0; j < 16; ++j) o[j] = (768 + j < IND) ? f2b(xp[j]) : (short)0;
    } else {                 // zero pad
#pragma unroll
        for (int j = 0; j < 16; ++j) o[j] = 0;
    }
    short* dst = &xb[(size_t)row * 800 + cb];
    *(short8_t*)dst = *(short8_t*)&o[0];
    *(short8_t*)(dst + 8) = *(short8_t*)&o[8];
}

// ---------------- weight transpose+pad cast via LDS tile ----------------
__global__ __launch_bounds__(256) void k_wt_t(const float* __restrict__ W,
                                              short* __restrict__ Wt,
                                              int K, int N, int Kp) {
    __shared__ short tile[32][33];
    int kb = blockIdx.x * 32, nb = blockIdx.y * 32;
    int tx = threadIdx.x & 31, ty = threadIdx.x >> 5;  // 32 x 8
#pragma unroll
    for (int r = 0; r < 32; r += 8) {
        int k = kb + ty + r;
        tile[ty + r][tx] = (k < K) ? f2b(W[(size_t)k * N + nb + tx]) : (short)0;
    }
    __syncthreads();
#pragma unroll
    for (int r = 0; r < 32; r += 8) {
        int n = nb + ty + r, k = kb + tx;
        Wt[(size_t)n * Kp + k] = tile[tx][ty + r];
    }
}

// ---------------- attention dot products ----------------
template<int HD>
__global__ __launch_bounds__(256) void att_dots(const short* __restrict__ hW,
                                                const float* __restrict__ att_s,
                                                const float* __restrict__ att_d,
                                                float* __restrict__ a_s,
                                                float* __restrict__ a_d) {
    const int CPL = HD / 64;
    int node = blockIdx.x * 4 + (threadIdx.x >> 6);
    int lane = threadIdx.x & 63;
    if (node >= NN) return;
    const short* row = hW + (size_t)node * HD + lane * CPL;
    float s = 0.f, d = 0.f;
#pragma unroll
    for (int j = 0; j < CPL; ++j) {
        float v = b2f(row[j]);
        s += v * att_s[lane * CPL + j];
        d += v * att_d[lane * CPL + j];
    }
#pragma unroll
    for (int off = 1; off < 16; off <<= 1) {
        s += __shfl_xor(s, off);
        d += __shfl_xor(d, off);
    }
    int h = lane >> 4;
    if ((lane & 15) == 0) {
        a_s[node * 4 + h] = s;
        a_d[node * 4 + h] = d;
    }
}

// ---------------- CSR build ----------------
__global__ void k_hist(const int* __restrict__ ei, int* __restrict__ deg) {
    int e = blockIdx.x * 256 + threadIdx.x;
    if (e >= NE) return;
    atomicAdd(&deg[ei[NE + e]], 1);
}

__global__ __launch_bounds__(256) void k_bsum(const int* __restrict__ deg,
                                              int* __restrict__ bsum) {
    int i = blockIdx.x * 256 + threadIdx.x;
    int v = (i < NN) ? deg[i] : 0;
#pragma unroll
    for (int off = 32; off; off >>= 1) v += __shfl_down(v, off);
    __shared__ int ws[4];
    if ((threadIdx.x & 63) == 0) ws[threadIdx.x >> 6] = v;
    __syncthreads();
    if (threadIdx.x == 0) bsum[blockIdx.x] = ws[0] + ws[1] + ws[2] + ws[3];
}

__global__ __launch_bounds__(256) void k_bscan(const int* __restrict__ bsum,
                                               int* __restrict__ boff) {
    int t = threadIdx.x;
    int orig = (t < SCAN_B) ? bsum[t] : 0;
    int v = orig;
    int lane = t & 63, wid = t >> 6;
#pragma unroll
    for (int off = 1; off < 64; off <<= 1) {
        int u = __shfl_up(v, off);
        if (lane >= off) v += u;
    }
    __shared__ int ws[4];
    if (lane == 63) ws[wid] = v;
    __syncthreads();
    int add = 0;
    for (int wq = 0; wq < wid; ++wq) add += ws[wq];
    if (t < SCAN_B) boff[t] = v + add - orig;  // exclusive
}

__global__ __launch_bounds__(256) void k_scan3(const int* __restrict__ deg,
                                               const int* __restrict__ boff,
                                               int* __restrict__ rowp,
                                               int* __restrict__ cursor) {
    int b = blockIdx.x;
    int i = b * 256 + threadIdx.x;
    int d = (i < NN) ? deg[i] : 0;
    int v = d;
    int lane = threadIdx.x & 63, wid = threadIdx.x >> 6;
#pragma unroll
    for (int off = 1; off < 64; off <<= 1) {
        int u = __shfl_up(v, off);
        if (lane >= off) v += u;
    }
    __shared__ int ws[4];
    if (lane == 63) ws[wid] = v;
    __syncthreads();
    int add = boff[b];
    for (int wq = 0; wq < wid; ++wq) add += ws[wq];
    int excl = add + v - d;
    if (i < NN) { rowp[i] = excl; cursor[i] = excl; }
    if (i == NN - 1) rowp[NN] = excl + d;
}

__global__ void k_scatter(const int* __restrict__ ei, int* __restrict__ cursor,
                          int* __restrict__ colidx) {
    int e = blockIdx.x * 256 + threadIdx.x;
    if (e >= NE) return;
    int s = ei[e], d = ei[NE + e];
    int pos = atomicAdd(&cursor[d], 1);
    colidx[pos] = s;
}

// ---------------- fused GAT aggregation (one wave per dst node), bf16 in/out ----------------
// Softmax shifted by self-loop score (exact). Masked 8-wide unroll for MLP.
template<int HD>
__global__ __launch_bounds__(256) void gat_agg(const short* __restrict__ hW,
                                               const float* __restrict__ a_s,
                                               const float* __restrict__ a_d,
                                               const int* __restrict__ row_ptr,
                                               const int* __restrict__ colidx,
                                               const float* __restrict__ bias,
                                               short* __restrict__ outp) {
    const int CPL = HD / 64;
    int node = blockIdx.x * 4 + (threadIdx.x >> 6);
    int lane = threadIdx.x & 63;
    if (node >= NN) return;
    int h = lane >> 4;
    int start = row_ptr[node], end = row_ptr[node + 1];
    float adst = a_d[node * 4 + h];
    float eself = lrelu(a_s[node * 4 + h] + adst);

    float z = 1.f;  // exp(eself - eself)
    float acc[CPL];
    {
        const short* row = hW + (size_t)node * HD + lane * CPL;
        if (CPL == 4) { short4 q = *(const short4*)row; acc[0]=b2f(q.x); acc[1]=b2f(q.y); acc[2]=b2f(q.z); acc[3]=b2f(q.w); }
        else          { short2 q = *(const short2*)row; acc[0]=b2f(q.x); acc[1]=b2f(q.y); }
    }
    for (int e = start; e < end; e += 8) {
        int sidx[8];
        float xs[8], ex[8];
#pragma unroll
        for (int q = 0; q < 8; ++q) {
            int ee = e + q;
            sidx[q] = colidx[ee < end ? ee : end - 1];
        }
#pragma unroll
        for (int q = 0; q < 8; ++q) xs[q] = a_s[sidx[q] * 4 + h];
        float v[8][CPL];
        if (CPL == 4) {
#pragma unroll
            for (int q = 0; q < 8; ++q) {
                short4 qq = *(const short4*)(hW + (size_t)sidx[q] * HD + lane * 4);
                v[q][0]=b2f(qq.x); v[q][1]=b2f(qq.y); v[q][2]=b2f(qq.z); v[q][3]=b2f(qq.w);
            }
        } else {
#pragma unroll
            for (int q = 0; q < 8; ++q) {
                short2 qq = *(const short2*)(hW + (size_t)sidx[q] * HD + lane * 2);
                v[q][0]=b2f(qq.x); v[q][1]=b2f(qq.y);
            }
        }
#pragma unroll
        for (int q = 0; q < 8; ++q) {
            float w = __expf(lrelu(xs[q] + adst) - eself);
            ex[q] = (e + q < end) ? w : 0.f;
        }
#pragma unroll
        for (int q = 0; q < 8; ++q) z += ex[q];
#pragma unroll
        for (int j = 0; j < CPL; ++j) {
            float a = 0.f;
#pragma unroll
            for (int q = 0; q < 8; ++q) a += ex[q] * v[q][j];
            acc[j] += a;
        }
    }
    float inv = 1.f / z;
    short* orow = outp + (size_t)node * HD + lane * CPL;
#pragma unroll
    for (int j = 0; j < CPL; ++j)
        orow[j] = f2b(fmaxf(acc[j] * inv + bias[lane * CPL + j], 0.f));
}

// ---------------- pooling + classifier heads ----------------
__global__ __launch_bounds__(512) void pool_head(const short* __restrict__ h2,
                                                 const int* __restrict__ batch,
                                                 const float* __restrict__ W_cls,
                                                 const float* __restrict__ b_cls,
                                                 const float* __restrict__ W_conf,
                                                 const float* __restrict__ b_conf,
                                                 float* __restrict__ out) {
    int b = blockIdx.x;
    int t = threadIdx.x & 127;
    int g = threadIdx.x >> 7;
    int lo = 0, hi = NN;
    while (lo < hi) { int mid = (lo + hi) >> 1; if (batch[mid] < b) lo = mid + 1; else hi = mid; }
    int start = lo;
    lo = 0; hi = NN;
    while (lo < hi) { int mid = (lo + hi) >> 1; if (batch[mid] < b + 1) lo = mid + 1; else hi = mid; }
    int end = lo;

    float acc = 0.f;
    for (int n = start + g; n < end; n += 4) acc += b2f(h2[(size_t)n * 128 + t]);
    __shared__ float se[4][128];
    se[g][t] = acc;
    __syncthreads();
    if (g == 0) {
        float emb = (se[0][t] + se[1][t] + se[2][t] + se[3][t]) /
                    fmaxf((float)(end - start), 1.f);
        se[0][t] = emb;
    }
    __syncthreads();
    if (threadIdx.x == 0) {
        float v = b_cls[0];
        for (int c = 0; c < 128; ++c) v += se[0][c] * W_cls[c * 2 + 0];
        out[b * 2 + 0] = v;
    } else if (threadIdx.x == 1) {
        float v = b_cls[1];
        for (int c = 0; c < 128; ++c) v += se[0][c] * W_cls[c * 2 + 1];
        out[b * 2 + 1] = v;
    } else if (threadIdx.x == 2) {
        float v = b_conf[0];
        for (int c = 0; c < 128; ++c) v += se[0][c] * W_conf[c];
        out[128 + b] = 1.f / (1.f + expf(-v));
    }
}

extern "C" void kernel_launch(void* const* d_in, const int* in_sizes, int n_in,
                              void* d_out, int out_size, void* d_ws, size_t ws_size,
                              hipStream_t stream) {
    const float* x        = (const float*)d_in[0];
    const int*   ei       = (const int*)d_in[1];
    const int*   batch    = (const int*)d_in[2];
    const float* W_in     = (const float*)d_in[3];
    const float* b_in     = (const float*)d_in[4];
    const float* W1       = (const float*)d_in[5];
    const float* att_src1 = (const float*)d_in[6];
    const float* att_dst1 = (const float*)d_in[7];
    const float* b1       = (const float*)d_in[8];
    const float* W2       = (const float*)d_in[9];
    const float* att_src2 = (const float*)d_in[10];
    const float* att_dst2 = (const float*)d_in[11];
    const float* b2       = (const float*)d_in[12];
    const float* W_cls    = (const float*)d_in[13];
    const float* b_cls    = (const float*)d_in[14];
    const float* W_conf   = (const float*)d_in[15];
    const float* b_conf   = (const float*)d_in[16];
    float* out = (float*)d_out;

    char* ws = (char*)d_ws;
    short* xb  = (short*)(ws + 0);            // [MPAD][800] 80,076,800 B
    short* hW1 = (short*)(ws + 0);            // [MPAD][256] (xb dead after GEMM2... see order)
    short* h1  = (short*)(ws + 25624576);
    short* hW2 = (short*)(ws + 51249152);     // [MPAD][128]
    short* h2  = (short*)(ws + 64061440);
    short* h0  = (short*)(ws + 80076800);     // [MPAD][256]
    size_t base = 105701376;
    short* Wt_in = (short*)(ws + base);               // [256][800]
    short* Wt1   = (short*)(ws + base + 409600);      // [256][256]
    short* Wt2   = (short*)(ws + base + 540672);      // [128][256]
    float* a_s1  = (float*)(ws + base + 606208);      // [50000][4] (reused layer 2)
    float* a_d1  = (float*)(ws + base + 1406208);
    int*   deg    = (int*)(ws + base + 2206208);
    int*   rowp   = (int*)(ws + base + 2406208);
    int*   cursor = (int*)(ws + base + 2606272);
    int*   colidx = (int*)(ws + base + 2806272);      // [800000]
    int*   bsum   = (int*)(ws + base + 6006272);      // [256]
    int*   boff   = (int*)(ws + base + 6007296);      // [256]

    // casts
    k_wt_t<<<dim3(25, 8), 256, 0, stream>>>(W_in, Wt_in, IND, 256, 800);
    k_wt_t<<<dim3(8, 8), 256, 0, stream>>>(W1, Wt1, 256, 256, 256);
    k_wt_t<<<dim3(8, 4), 256, 0, stream>>>(W2, Wt2, 256, 128, 256);
    k_cast_pad<<<(NN * 50 + 255) / 256, 256, 0, stream>>>(x, xb);

    // CSR build (hierarchical scan)
    hipMemsetAsync(deg, 0, NN * sizeof(int), stream);
    k_hist<<<NE / 256, 256, 0, stream>>>(ei, deg);
    k_bsum<<<SCAN_B, 256, 0, stream>>>(deg, bsum);
    k_bscan<<<1, 256, 0, stream>>>(bsum, boff);
    k_scan3<<<SCAN_B, 256, 0, stream>>>(deg, boff, rowp, cursor);
    k_scatter<<<NE / 256, 256, 0, stream>>>(ei, cursor, colidx);

    // h0 = relu(xb @ Wt_in^T + b_in)
    gemm_lds<1, 1><<<dim3(391, 2), 256, 0, stream>>>(xb, Wt_in, b_in, h0, NN, 800, 256);
    // hW1 = h0 @ W1 (overwrites xb region — xb dead)
    gemm_lds<0, 0><<<dim3(391, 2), 256, 0, stream>>>(h0, Wt1, nullptr, hW1, NN, 256, 256);
    att_dots<256><<<12500, 256, 0, stream>>>(hW1, att_src1, att_dst1, a_s1, a_d1);
    gat_agg<256><<<12500, 256, 0, stream>>>(hW1, a_s1, a_d1, rowp, colidx, b1, h1);
    // hW2 = h1 @ W2
    gemm_lds<0, 0><<<dim3(391, 1), 256, 0, stream>>>(h1, Wt2, nullptr, hW2, NN, 256, 128);
    att_dots<128><<<12500, 256, 0, stream>>>(hW2, att_src2, att_dst2, a_s1, a_d1);
    gat_agg<128><<<12500, 256, 0, stream>>>(hW2, a_s1, a_d1, rowp, colidx, b2, h2);
    pool_head<<<NB, 512, 0, stream>>>(h2, batch, W_cls, b_cls, W_conf, b_conf, out);
}

// Round 6
// 425.692 us; speedup vs baseline: 1.3401x; 1.0048x over previous
//
#include <hip/hip_runtime.h>
#include <math.h>

#define NN 50000
#define NE 800000
#define NB 64
#define IND 773
#define MPAD 50048   // 128-row-padded M
#define SCAN_B 196   // ceil(NN/256)

typedef __attribute__((ext_vector_type(8))) short short8_t;
typedef __attribute__((ext_vector_type(4))) float f32x4;

__device__ __forceinline__ float lrelu(float x) { return x > 0.f ? x : 0.2f * x; }
__device__ __forceinline__ short f2b(float f) {
    unsigned u = __float_as_uint(f);
    unsigned r = (u + 0x7fffu + ((u >> 16) & 1u)) >> 16;  // RNE
    return (short)r;
}
__device__ __forceinline__ float b2f(short s) {
    return __uint_as_float(((unsigned)(unsigned short)s) << 16);
}

#define GLOAD16(g, l) __builtin_amdgcn_global_load_lds(                         \
    (const __attribute__((address_space(1))) void*)(g),                         \
    (__attribute__((address_space(3))) void*)(l), 16, 0, 0)

// ---------------- bf16 MFMA GEMM, m97 structure ----------------
template<int RELU, int HASB>
__global__ __launch_bounds__(256) void gemm_lds(const short* __restrict__ A,
                                                const short* __restrict__ Bt,
                                                const float* __restrict__ bias,
                                                short* __restrict__ C,
                                                int M, int K, int N) {
    __shared__ short As[128 * 32];
    __shared__ short Bs[128 * 32];
    const int t = threadIdx.x;
    const int w = t >> 6, l = t & 63;
    const int l15 = l & 15, lh = l >> 4;
    const int bm = blockIdx.x * 128, bn = blockIdx.y * 128;
    const int wr = (w >> 1) * 64, wc = (w & 1) * 64;

    const short* aG = A + (size_t)(bm + w * 32 + (l >> 2)) * K + (l & 3) * 8;
    const short* bG = Bt + (size_t)(bn + w * 32 + (l >> 2)) * K + (l & 3) * 8;
    short* aL = As + (w * 32) * 32;
    short* bL = Bs + (w * 32) * 32;

    f32x4 acc[4][4];
#pragma unroll
    for (int i = 0; i < 4; ++i)
#pragma unroll
        for (int j = 0; j < 4; ++j) acc[i][j] = (f32x4){0.f, 0.f, 0.f, 0.f};

    for (int k0 = 0; k0 < K; k0 += 32) {
        __syncthreads();
        GLOAD16(aG + k0, aL);
        GLOAD16(aG + (size_t)16 * K + k0, aL + 16 * 32);
        GLOAD16(bG + k0, bL);
        GLOAD16(bG + (size_t)16 * K + k0, bL + 16 * 32);
        __syncthreads();
        short8_t af[4], bfr[4];
#pragma unroll
        for (int mi = 0; mi < 4; ++mi)
            af[mi] = *(const short8_t*)&As[(wr + mi * 16 + l15) * 32 + lh * 8];
#pragma unroll
        for (int ni = 0; ni < 4; ++ni)
            bfr[ni] = *(const short8_t*)&Bs[(wc + ni * 16 + l15) * 32 + lh * 8];
#pragma unroll
        for (int mi = 0; mi < 4; ++mi)
#pragma unroll
            for (int ni = 0; ni < 4; ++ni)
                acc[mi][ni] = __builtin_amdgcn_mfma_f32_16x16x32_bf16(af[mi], bfr[ni], acc[mi][ni], 0, 0, 0);
    }

#pragma unroll
    for (int mi = 0; mi < 4; ++mi) {
#pragma unroll
        for (int r = 0; r < 4; ++r) {
            int grow = bm + wr + mi * 16 + lh * 4 + r;
            if (grow >= M) continue;
#pragma unroll
            for (int ni = 0; ni < 4; ++ni) {
                int gcol = bn + wc + ni * 16 + l15;
                float v = acc[mi][ni][r];
                if (HASB) v += bias[gcol];
                if (RELU) v = fmaxf(v, 0.f);
                C[(size_t)grow * N + gcol] = f2b(v);
            }
        }
    }
}

// ---------------- x: fp32 [NN][773] -> bf16 [MPAD][800], branchless 16 cols/thread ----------------
__global__ __launch_bounds__(256) void k_cast_pad(const float* __restrict__ x,
                                                  short* __restrict__ xb) {
    int idx = blockIdx.x * 256 + threadIdx.x;  // 16 cols per thread
    if (idx >= NN * 50) return;
    int row = idx / 50;
    int c16 = idx - row * 50;
    int cb = c16 * 16;
    const float* xp = x + (size_t)row * IND + cb;
    short o[16];
    if (c16 < 48) {          // cb <= 752: all 16 in-range, unchecked
        float v[16];
#pragma unroll
        for (int j = 0; j < 16; ++j) v[j] = xp[j];
#pragma unroll
        for (int j = 0; j < 16; ++j) o[j] = f2b(v[j]);
    } else if (c16 == 48) {  // cb = 768: 5 valid
#pragma unroll
        for (int j = 0; j < 16; ++j) o[j] = (768 + j < IND) ? f2b(xp[j]) : (short)0;
    } else {                 // zero pad
#pragma unroll
        for (int j = 0; j < 16; ++j) o[j] = 0;
    }
    short* dst = &xb[(size_t)row * 800 + cb];
    *(short8_t*)dst = *(short8_t*)&o[0];
    *(short8_t*)(dst + 8) = *(short8_t*)&o[8];
}

// ---------------- weight transpose+pad cast via LDS tile ----------------
__global__ __launch_bounds__(256) void k_wt_t(const float* __restrict__ W,
                                              short* __restrict__ Wt,
                                              int K, int N, int Kp) {
    __shared__ short tile[32][33];
    int kb = blockIdx.x * 32, nb = blockIdx.y * 32;
    int tx = threadIdx.x & 31, ty = threadIdx.x >> 5;  // 32 x 8
#pragma unroll
    for (int r = 0; r < 32; r += 8) {
        int k = kb + ty + r;
        tile[ty + r][tx] = (k < K) ? f2b(W[(size_t)k * N + nb + tx]) : (short)0;
    }
    __syncthreads();
#pragma unroll
    for (int r = 0; r < 32; r += 8) {
        int n = nb + ty + r, k = kb + tx;
        Wt[(size_t)n * Kp + k] = tile[tx][ty + r];
    }
}

// ---------------- attention dot products ----------------
template<int HD>
__global__ __launch_bounds__(256) void att_dots(const short* __restrict__ hW,
                                                const float* __restrict__ att_s,
                                                const float* __restrict__ att_d,
                                                float* __restrict__ a_s,
                                                float* __restrict__ a_d) {
    const int CPL = HD / 64;
    int node = blockIdx.x * 4 + (threadIdx.x >> 6);
    int lane = threadIdx.x & 63;
    if (node >= NN) return;
    const short* row = hW + (size_t)node * HD + lane * CPL;
    float s = 0.f, d = 0.f;
#pragma unroll
    for (int j = 0; j < CPL; ++j) {
        float v = b2f(row[j]);
        s += v * att_s[lane * CPL + j];
        d += v * att_d[lane * CPL + j];
    }
#pragma unroll
    for (int off = 1; off < 16; off <<= 1) {
        s += __shfl_xor(s, off);
        d += __shfl_xor(d, off);
    }
    int h = lane >> 4;
    if ((lane & 15) == 0) {
        a_s[node * 4 + h] = s;
        a_d[node * 4 + h] = d;
    }
}

// ---------------- CSR build ----------------
__global__ __launch_bounds__(256) void k_zero(int* __restrict__ p, int n) {
    int i = blockIdx.x * 256 + threadIdx.x;
    if (i < n) p[i] = 0;
}

__global__ void k_hist(const int* __restrict__ ei, int* __restrict__ deg) {
    int e = blockIdx.x * 256 + threadIdx.x;
    if (e >= NE) return;
    atomicAdd(&deg[ei[NE + e]], 1);
}

__global__ __launch_bounds__(256) void k_bsum(const int* __restrict__ deg,
                                              int* __restrict__ bsum) {
    int i = blockIdx.x * 256 + threadIdx.x;
    int v = (i < NN) ? deg[i] : 0;
#pragma unroll
    for (int off = 32; off; off >>= 1) v += __shfl_down(v, off);
    __shared__ int ws[4];
    if ((threadIdx.x & 63) == 0) ws[threadIdx.x >> 6] = v;
    __syncthreads();
    if (threadIdx.x == 0) bsum[blockIdx.x] = ws[0] + ws[1] + ws[2] + ws[3];
}

__global__ __launch_bounds__(256) void k_bscan(const int* __restrict__ bsum,
                                               int* __restrict__ boff) {
    int t = threadIdx.x;
    int orig = (t < SCAN_B) ? bsum[t] : 0;
    int v = orig;
    int lane = t & 63, wid = t >> 6;
#pragma unroll
    for (int off = 1; off < 64; off <<= 1) {
        int u = __shfl_up(v, off);
        if (lane >= off) v += u;
    }
    __shared__ int ws[4];
    if (lane == 63) ws[wid] = v;
    __syncthreads();
    int add = 0;
    for (int wq = 0; wq < wid; ++wq) add += ws[wq];
    if (t < SCAN_B) boff[t] = v + add - orig;  // exclusive
}

__global__ __launch_bounds__(256) void k_scan3(const int* __restrict__ deg,
                                               const int* __restrict__ boff,
                                               int* __restrict__ rowp,
                                               int* __restrict__ cursor) {
    int b = blockIdx.x;
    int i = b * 256 + threadIdx.x;
    int d = (i < NN) ? deg[i] : 0;
    int v = d;
    int lane = threadIdx.x & 63, wid = threadIdx.x >> 6;
#pragma unroll
    for (int off = 1; off < 64; off <<= 1) {
        int u = __shfl_up(v, off);
        if (lane >= off) v += u;
    }
    __shared__ int ws[4];
    if (lane == 63) ws[wid] = v;
    __syncthreads();
    int add = boff[b];
    for (int wq = 0; wq < wid; ++wq) add += ws[wq];
    int excl = add + v - d;
    if (i < NN) { rowp[i] = excl; cursor[i] = excl; }
    if (i == NN - 1) rowp[NN] = excl + d;
}

__global__ void k_scatter(const int* __restrict__ ei, int* __restrict__ cursor,
                          int* __restrict__ colidx) {
    int e = blockIdx.x * 256 + threadIdx.x;
    if (e >= NE) return;
    int s = ei[e], d = ei[NE + e];
    int pos = atomicAdd(&cursor[d], 1);
    colidx[pos] = s;
}

// ---------------- fused GAT aggregation (one wave per dst node), bf16 in/out ----------------
// Softmax shifted by self-loop score (exact). Masked 8-wide unroll for MLP.
template<int HD>
__global__ __launch_bounds__(256) void gat_agg(const short* __restrict__ hW,
                                               const float* __restrict__ a_s,
                                               const float* __restrict__ a_d,
                                               const int* __restrict__ row_ptr,
                                               const int* __restrict__ colidx,
                                               const float* __restrict__ bias,
                                               short* __restrict__ outp) {
    const int CPL = HD / 64;
    int node = blockIdx.x * 4 + (threadIdx.x >> 6);
    int lane = threadIdx.x & 63;
    if (node >= NN) return;
    int h = lane >> 4;
    int start = row_ptr[node], end = row_ptr[node + 1];
    float adst = a_d[node * 4 + h];
    float eself = lrelu(a_s[node * 4 + h] + adst);

    float z = 1.f;  // exp(eself - eself)
    float acc[CPL];
    {
        const short* row = hW + (size_t)node * HD + lane * CPL;
        if (CPL == 4) { short4 q = *(const short4*)row; acc[0]=b2f(q.x); acc[1]=b2f(q.y); acc[2]=b2f(q.z); acc[3]=b2f(q.w); }
        else          { short2 q = *(const short2*)row; acc[0]=b2f(q.x); acc[1]=b2f(q.y); }
    }
    for (int e = start; e < end; e += 8) {
        int sidx[8];
        float xs[8], ex[8];
#pragma unroll
        for (int q = 0; q < 8; ++q) {
            int ee = e + q;
            sidx[q] = colidx[ee < end ? ee : end - 1];
        }
#pragma unroll
        for (int q = 0; q < 8; ++q) xs[q] = a_s[sidx[q] * 4 + h];
        float v[8][CPL];
        if (CPL == 4) {
#pragma unroll
            for (int q = 0; q < 8; ++q) {
                short4 qq = *(const short4*)(hW + (size_t)sidx[q] * HD + lane * 4);
                v[q][0]=b2f(qq.x); v[q][1]=b2f(qq.y); v[q][2]=b2f(qq.z); v[q][3]=b2f(qq.w);
            }
        } else {
#pragma unroll
            for (int q = 0; q < 8; ++q) {
                short2 qq = *(const short2*)(hW + (size_t)sidx[q] * HD + lane * 2);
                v[q][0]=b2f(qq.x); v[q][1]=b2f(qq.y);
            }
        }
#pragma unroll
        for (int q = 0; q < 8; ++q) {
            float w = __expf(lrelu(xs[q] + adst) - eself);
            ex[q] = (e + q < end) ? w : 0.f;
        }
#pragma unroll
        for (int q = 0; q < 8; ++q) z += ex[q];
#pragma unroll
        for (int j = 0; j < CPL; ++j) {
            float a = 0.f;
#pragma unroll
            for (int q = 0; q < 8; ++q) a += ex[q] * v[q][j];
            acc[j] += a;
        }
    }
    float inv = 1.f / z;
    short* orow = outp + (size_t)node * HD + lane * CPL;
#pragma unroll
    for (int j = 0; j < CPL; ++j)
        orow[j] = f2b(fmaxf(acc[j] * inv + bias[lane * CPL + j], 0.f));
}

// ---------------- pooling + classifier heads ----------------
__global__ __launch_bounds__(512) void pool_head(const short* __restrict__ h2,
                                                 const int* __restrict__ batch,
                                                 const float* __restrict__ W_cls,
                                                 const float* __restrict__ b_cls,
                                                 const float* __restrict__ W_conf,
                                                 const float* __restrict__ b_conf,
                                                 float* __restrict__ out) {
    int b = blockIdx.x;
    int t = threadIdx.x & 127;
    int g = threadIdx.x >> 7;
    int lo = 0, hi = NN;
    while (lo < hi) { int mid = (lo + hi) >> 1; if (batch[mid] < b) lo = mid + 1; else hi = mid; }
    int start = lo;
    lo = 0; hi = NN;
    while (lo < hi) { int mid = (lo + hi) >> 1; if (batch[mid] < b + 1) lo = mid + 1; else hi = mid; }
    int end = lo;

    float acc = 0.f;
    for (int n = start + g; n < end; n += 4) acc += b2f(h2[(size_t)n * 128 + t]);
    __shared__ float se[4][128];
    se[g][t] = acc;
    __syncthreads();
    if (g == 0) {
        float emb = (se[0][t] + se[1][t] + se[2][t] + se[3][t]) /
                    fmaxf((float)(end - start), 1.f);
        se[0][t] = emb;
    }
    __syncthreads();
    if (threadIdx.x == 0) {
        float v = b_cls[0];
        for (int c = 0; c < 128; ++c) v += se[0][c] * W_cls[c * 2 + 0];
        out[b * 2 + 0] = v;
    } else if (threadIdx.x == 1) {
        float v = b_cls[1];
        for (int c = 0; c < 128; ++c) v += se[0][c] * W_cls[c * 2 + 1];
        out[b * 2 + 1] = v;
    } else if (threadIdx.x == 2) {
        float v = b_conf[0];
        for (int c = 0; c < 128; ++c) v += se[0][c] * W_conf[c];
        out[128 + b] = 1.f / (1.f + expf(-v));
    }
}

extern "C" void kernel_launch(void* const* d_in, const int* in_sizes, int n_in,
                              void* d_out, int out_size, void* d_ws, size_t ws_size,
                              hipStream_t stream) {
    const float* x        = (const float*)d_in[0];
    const int*   ei       = (const int*)d_in[1];
    const int*   batch    = (const int*)d_in[2];
    const float* W_in     = (const float*)d_in[3];
    const float* b_in     = (const float*)d_in[4];
    const float* W1       = (const float*)d_in[5];
    const float* att_src1 = (const float*)d_in[6];
    const float* att_dst1 = (const float*)d_in[7];
    const float* b1       = (const float*)d_in[8];
    const float* W2       = (const float*)d_in[9];
    const float* att_src2 = (const float*)d_in[10];
    const float* att_dst2 = (const float*)d_in[11];
    const float* b2       = (const float*)d_in[12];
    const float* W_cls    = (const float*)d_in[13];
    const float* b_cls    = (const float*)d_in[14];
    const float* W_conf   = (const float*)d_in[15];
    const float* b_conf   = (const float*)d_in[16];
    float* out = (float*)d_out;

    char* ws = (char*)d_ws;
    short* xb  = (short*)(ws + 0);            // [MPAD][800] 80,076,800 B
    short* hW1 = (short*)(ws + 0);            // [MPAD][256] (xb dead after GEMM2)
    short* h1  = (short*)(ws + 25624576);
    short* hW2 = (short*)(ws + 51249152);     // [MPAD][128]
    short* h2  = (short*)(ws + 64061440);
    short* h0  = (short*)(ws + 80076800);     // [MPAD][256]
    size_t base = 105701376;
    short* Wt_in = (short*)(ws + base);               // [256][800]
    short* Wt1   = (short*)(ws + base + 409600);      // [256][256]
    short* Wt2   = (short*)(ws + base + 540672);      // [128][256]
    float* a_s1  = (float*)(ws + base + 606208);      // [50000][4] (reused layer 2)
    float* a_d1  = (float*)(ws + base + 1406208);
    int*   deg    = (int*)(ws + base + 2206208);
    int*   rowp   = (int*)(ws + base + 2406208);
    int*   cursor = (int*)(ws + base + 2606272);
    int*   colidx = (int*)(ws + base + 2806272);      // [800000]
    int*   bsum   = (int*)(ws + base + 6006272);      // [256]
    int*   boff   = (int*)(ws + base + 6007296);      // [256]

    // casts
    k_wt_t<<<dim3(25, 8), 256, 0, stream>>>(W_in, Wt_in, IND, 256, 800);
    k_wt_t<<<dim3(8, 8), 256, 0, stream>>>(W1, Wt1, 256, 256, 256);
    k_wt_t<<<dim3(8, 4), 256, 0, stream>>>(W2, Wt2, 256, 128, 256);
    k_cast_pad<<<(NN * 50 + 255) / 256, 256, 0, stream>>>(x, xb);

    // CSR build (hierarchical scan); own zero kernel — runtime fill kernel ran 1-WG (88us!)
    k_zero<<<SCAN_B, 256, 0, stream>>>(deg, NN);
    k_hist<<<NE / 256, 256, 0, stream>>>(ei, deg);
    k_bsum<<<SCAN_B, 256, 0, stream>>>(deg, bsum);
    k_bscan<<<1, 256, 0, stream>>>(bsum, boff);
    k_scan3<<<SCAN_B, 256, 0, stream>>>(deg, boff, rowp, cursor);
    k_scatter<<<NE / 256, 256, 0, stream>>>(ei, cursor, colidx);

    // h0 = relu(xb @ Wt_in^T + b_in)
    gemm_lds<1, 1><<<dim3(391, 2), 256, 0, stream>>>(xb, Wt_in, b_in, h0, NN, 800, 256);
    // hW1 = h0 @ W1 (overwrites xb region — xb dead)
    gemm_lds<0, 0><<<dim3(391, 2), 256, 0, stream>>>(h0, Wt1, nullptr, hW1, NN, 256, 256);
    att_dots<256><<<12500, 256, 0, stream>>>(hW1, att_src1, att_dst1, a_s1, a_d1);
    gat_agg<256><<<12500, 256, 0, stream>>>(hW1, a_s1, a_d1, rowp, colidx, b1, h1);
    // hW2 = h1 @ W2
    gemm_lds<0, 0><<<dim3(391, 1), 256, 0, stream>>>(h1, Wt2, nullptr, hW2, NN, 256, 128);
    att_dots<128><<<12500, 256, 0, stream>>>(hW2, att_src2, att_dst2, a_s1, a_d1);
    gat_agg<128><<<12500, 256, 0, stream>>>(hW2, a_s1, a_d1, rowp, colidx, b2, h2);
    pool_head<<<NB, 512, 0, stream>>>(h2, batch, W_cls, b_cls, W_conf, b_conf, out);
}

// Round 7
// 409.307 us; speedup vs baseline: 1.3938x; 1.0400x over previous
//
#include <hip/hip_runtime.h>
#include <math.h>

#define NN 50000
#define NE 800000
#define NB 64
#define IND 773
#define MPAD 50048   // 128-row-padded M
#define SCAN_B 196   // ceil(NN/256)

typedef __attribute__((ext_vector_type(8))) short short8_t;
typedef __attribute__((ext_vector_type(4))) float f32x4;

__device__ __forceinline__ float lrelu(float x) { return x > 0.f ? x : 0.2f * x; }
__device__ __forceinline__ short f2b(float f) {
    unsigned u = __float_as_uint(f);
    unsigned r = (u + 0x7fffu + ((u >> 16) & 1u)) >> 16;  // RNE
    return (short)r;
}
__device__ __forceinline__ float b2f(short s) {
    return __uint_as_float(((unsigned)(unsigned short)s) << 16);
}

#define GLOAD16(g, l) __builtin_amdgcn_global_load_lds(                         \
    (const __attribute__((address_space(1))) void*)(g),                         \
    (__attribute__((address_space(3))) void*)(l), 16, 0, 0)

// ---------------- GEMM1 fused with fp32->bf16 cast: h0 = relu(x @ Wt_in^T + b_in) ----------------
// x fp32 [NN][773] read directly (guarded), B via global_load_lds. 128x256 tile, 512 thr / 8 waves.
__global__ __launch_bounds__(512) void gemm_a(const float* __restrict__ X,
                                              const short* __restrict__ Bt,   // Wt_in [256][800]
                                              const float* __restrict__ bias,
                                              short* __restrict__ C) {        // h0 [MPAD][256]
    const int K = 800, N = 256;
    __shared__ short As[128 * 32];   // 8 KB
    __shared__ short Bs[256 * 32];   // 16 KB
    const int t = threadIdx.x;
    const int w = t >> 6, l = t & 63;
    const int l15 = l & 15, lh = l >> 4;
    const int bm = blockIdx.x * 128;
    const int wr = (w >> 2) * 64, wc = (w & 3) * 64;

    const short* bG = Bt + (size_t)(t >> 2) * K + (t & 3) * 8;  // rows 0..127 (+128 on call 2)
    short* bLu = Bs + w * 512;  // wave-uniform; HW adds lane*16B

    f32x4 acc[4][4];
#pragma unroll
    for (int i = 0; i < 4; ++i)
#pragma unroll
        for (int j = 0; j < 4; ++j) acc[i][j] = (f32x4){0.f, 0.f, 0.f, 0.f};

    for (int k0 = 0; k0 < K; k0 += 32) {
        __syncthreads();
        GLOAD16(bG + k0, bLu);
        GLOAD16(bG + (size_t)128 * K + k0, bLu + 128 * 32);
        // A: 128 rows x 32 cols fp32 -> bf16, 4 col-pairs per thread
#pragma unroll
        for (int i = 0; i < 4; ++i) {
            int fid = i * 512 + t;      // 0..2047
            int row = fid >> 4;         // 0..127
            int cp = fid & 15;          // col pair
            int gm = bm + row;
            int gk = k0 + cp * 2;
            const float* xp = X + (size_t)gm * IND + gk;
            bool rowok = (gm < NN);
            float v0 = (rowok && gk < IND) ? xp[0] : 0.f;
            float v1 = (rowok && gk + 1 < IND) ? xp[1] : 0.f;
            unsigned pk = ((unsigned)(unsigned short)f2b(v0)) |
                          (((unsigned)(unsigned short)f2b(v1)) << 16);
            *(unsigned*)&As[row * 32 + cp * 2] = pk;
        }
        __syncthreads();
        short8_t af[4], bfr[4];
#pragma unroll
        for (int mi = 0; mi < 4; ++mi)
            af[mi] = *(const short8_t*)&As[(wr + mi * 16 + l15) * 32 + lh * 8];
#pragma unroll
        for (int ni = 0; ni < 4; ++ni)
            bfr[ni] = *(const short8_t*)&Bs[(wc + ni * 16 + l15) * 32 + lh * 8];
#pragma unroll
        for (int mi = 0; mi < 4; ++mi)
#pragma unroll
            for (int ni = 0; ni < 4; ++ni)
                acc[mi][ni] = __builtin_amdgcn_mfma_f32_16x16x32_bf16(af[mi], bfr[ni], acc[mi][ni], 0, 0, 0);
    }
#pragma unroll
    for (int mi = 0; mi < 4; ++mi) {
#pragma unroll
        for (int r = 0; r < 4; ++r) {
            int grow = bm + wr + mi * 16 + lh * 4 + r;
            if (grow >= NN) continue;
#pragma unroll
            for (int ni = 0; ni < 4; ++ni) {
                int gcol = wc + ni * 16 + l15;
                float v = fmaxf(acc[mi][ni][r] + bias[gcol], 0.f);
                C[(size_t)grow * N + gcol] = f2b(v);
            }
        }
    }
}

// ---------------- GEMM2 fused with att dots (D=64): hW1 = h0 @ Wt1^T; a_s/a_d ----------------
__global__ __launch_bounds__(512) void gemm_b(const short* __restrict__ A,    // h0 [MPAD][256]
                                              const short* __restrict__ Bt,   // Wt1 [256][256]
                                              const float* __restrict__ att_s,
                                              const float* __restrict__ att_d,
                                              short* __restrict__ C,          // hW1
                                              float* __restrict__ a_s,
                                              float* __restrict__ a_d) {
    const int K = 256, N = 256;
    __shared__ short As[128 * 32];
    __shared__ short Bs[256 * 32];
    const int t = threadIdx.x;
    const int w = t >> 6, l = t & 63;
    const int l15 = l & 15, lh = l >> 4;
    const int bm = blockIdx.x * 128;
    const int wr = (w >> 2) * 64, wc = (w & 3) * 64;

    const short* aG = A + (size_t)(bm + (t >> 2)) * K + (t & 3) * 8;
    const short* bG = Bt + (size_t)(t >> 2) * K + (t & 3) * 8;
    short* aLu = As + w * 512;
    short* bLu = Bs + w * 512;

    f32x4 acc[4][4];
#pragma unroll
    for (int i = 0; i < 4; ++i)
#pragma unroll
        for (int j = 0; j < 4; ++j) acc[i][j] = (f32x4){0.f, 0.f, 0.f, 0.f};

    for (int k0 = 0; k0 < K; k0 += 32) {
        __syncthreads();
        GLOAD16(aG + k0, aLu);
        GLOAD16(bG + k0, bLu);
        GLOAD16(bG + (size_t)128 * K + k0, bLu + 128 * 32);
        __syncthreads();
        short8_t af[4], bfr[4];
#pragma unroll
        for (int mi = 0; mi < 4; ++mi)
            af[mi] = *(const short8_t*)&As[(wr + mi * 16 + l15) * 32 + lh * 8];
#pragma unroll
        for (int ni = 0; ni < 4; ++ni)
            bfr[ni] = *(const short8_t*)&Bs[(wc + ni * 16 + l15) * 32 + lh * 8];
#pragma unroll
        for (int mi = 0; mi < 4; ++mi)
#pragma unroll
            for (int ni = 0; ni < 4; ++ni)
                acc[mi][ni] = __builtin_amdgcn_mfma_f32_16x16x32_bf16(af[mi], bfr[ni], acc[mi][ni], 0, 0, 0);
    }
    const int head = wc >> 6;  // wave's 64 cols = exactly one head
    float sa[4], sd[4];
#pragma unroll
    for (int ni = 0; ni < 4; ++ni) {
        sa[ni] = att_s[head * 64 + ni * 16 + l15];
        sd[ni] = att_d[head * 64 + ni * 16 + l15];
    }
#pragma unroll
    for (int mi = 0; mi < 4; ++mi) {
#pragma unroll
        for (int r = 0; r < 4; ++r) {
            int grow = bm + wr + mi * 16 + lh * 4 + r;
            float s = acc[mi][0][r] * sa[0] + acc[mi][1][r] * sa[1] +
                      acc[mi][2][r] * sa[2] + acc[mi][3][r] * sa[3];
            float d = acc[mi][0][r] * sd[0] + acc[mi][1][r] * sd[1] +
                      acc[mi][2][r] * sd[2] + acc[mi][3][r] * sd[3];
#pragma unroll
            for (int off = 1; off < 16; off <<= 1) {
                s += __shfl_xor(s, off);
                d += __shfl_xor(d, off);
            }
            if (grow < NN) {
                if (l15 == 0) { a_s[grow * 4 + head] = s; a_d[grow * 4 + head] = d; }
#pragma unroll
                for (int ni = 0; ni < 4; ++ni)
                    C[(size_t)grow * N + wc + ni * 16 + l15] = f2b(acc[mi][ni][r]);
            }
        }
    }
}

// ---------------- GEMM3 fused with att dots (D=32): hW2 = h1 @ Wt2^T ----------------
__global__ __launch_bounds__(256) void gemm_c(const short* __restrict__ A,    // h1 [MPAD][256]
                                              const short* __restrict__ Bt,   // Wt2 [128][256]
                                              const float* __restrict__ att_s,
                                              const float* __restrict__ att_d,
                                              short* __restrict__ C,          // hW2 [MPAD][128]
                                              float* __restrict__ a_s,
                                              float* __restrict__ a_d) {
    const int K = 256, N = 128;
    __shared__ short As[128 * 32];
    __shared__ short Bs[128 * 32];
    const int t = threadIdx.x;
    const int w = t >> 6, l = t & 63;
    const int l15 = l & 15, lh = l >> 4;
    const int bm = blockIdx.x * 128;
    const int wr = (w >> 1) * 64, wc = (w & 1) * 64;

    const short* aG = A + (size_t)(bm + w * 32 + (l >> 2)) * K + (l & 3) * 8;
    const short* bG = Bt + (size_t)(w * 32 + (l >> 2)) * K + (l & 3) * 8;
    short* aL = As + (w * 32) * 32;
    short* bL = Bs + (w * 32) * 32;

    f32x4 acc[4][4];
#pragma unroll
    for (int i = 0; i < 4; ++i)
#pragma unroll
        for (int j = 0; j < 4; ++j) acc[i][j] = (f32x4){0.f, 0.f, 0.f, 0.f};

    for (int k0 = 0; k0 < K; k0 += 32) {
        __syncthreads();
        GLOAD16(aG + k0, aL);
        GLOAD16(aG + (size_t)16 * K + k0, aL + 16 * 32);
        GLOAD16(bG + k0, bL);
        GLOAD16(bG + (size_t)16 * K + k0, bL + 16 * 32);
        __syncthreads();
        short8_t af[4], bfr[4];
#pragma unroll
        for (int mi = 0; mi < 4; ++mi)
            af[mi] = *(const short8_t*)&As[(wr + mi * 16 + l15) * 32 + lh * 8];
#pragma unroll
        for (int ni = 0; ni < 4; ++ni)
            bfr[ni] = *(const short8_t*)&Bs[(wc + ni * 16 + l15) * 32 + lh * 8];
#pragma unroll
        for (int mi = 0; mi < 4; ++mi)
#pragma unroll
            for (int ni = 0; ni < 4; ++ni)
                acc[mi][ni] = __builtin_amdgcn_mfma_f32_16x16x32_bf16(af[mi], bfr[ni], acc[mi][ni], 0, 0, 0);
    }
    // wave covers 64 cols = 2 heads of 32; ni 0,1 -> head h0; ni 2,3 -> head h0+1
    const int h0 = wc >> 5;
    float sa[4], sd[4];
#pragma unroll
    for (int ni = 0; ni < 4; ++ni) {
        int idx = (h0 + (ni >> 1)) * 32 + (ni & 1) * 16 + l15;
        sa[ni] = att_s[idx];
        sd[ni] = att_d[idx];
    }
#pragma unroll
    for (int mi = 0; mi < 4; ++mi) {
#pragma unroll
        for (int r = 0; r < 4; ++r) {
            int grow = bm + wr + mi * 16 + lh * 4 + r;
            float s0 = acc[mi][0][r] * sa[0] + acc[mi][1][r] * sa[1];
            float s1 = acc[mi][2][r] * sa[2] + acc[mi][3][r] * sa[3];
            float d0 = acc[mi][0][r] * sd[0] + acc[mi][1][r] * sd[1];
            float d1 = acc[mi][2][r] * sd[2] + acc[mi][3][r] * sd[3];
#pragma unroll
            for (int off = 1; off < 16; off <<= 1) {
                s0 += __shfl_xor(s0, off); s1 += __shfl_xor(s1, off);
                d0 += __shfl_xor(d0, off); d1 += __shfl_xor(d1, off);
            }
            if (grow < NN) {
                if (l15 == 0) {
                    a_s[grow * 4 + h0] = s0; a_s[grow * 4 + h0 + 1] = s1;
                    a_d[grow * 4 + h0] = d0; a_d[grow * 4 + h0 + 1] = d1;
                }
#pragma unroll
                for (int ni = 0; ni < 4; ++ni)
                    C[(size_t)grow * N + wc + ni * 16 + l15] = f2b(acc[mi][ni][r]);
            }
        }
    }
}

// ---------------- weight transpose+pad cast via LDS tile ----------------
__global__ __launch_bounds__(256) void k_wt_t(const float* __restrict__ W,
                                              short* __restrict__ Wt,
                                              int K, int N, int Kp) {
    __shared__ short tile[32][33];
    int kb = blockIdx.x * 32, nb = blockIdx.y * 32;
    int tx = threadIdx.x & 31, ty = threadIdx.x >> 5;  // 32 x 8
#pragma unroll
    for (int r = 0; r < 32; r += 8) {
        int k = kb + ty + r;
        tile[ty + r][tx] = (k < K) ? f2b(W[(size_t)k * N + nb + tx]) : (short)0;
    }
    __syncthreads();
#pragma unroll
    for (int r = 0; r < 32; r += 8) {
        int n = nb + ty + r, k = kb + tx;
        Wt[(size_t)n * Kp + k] = tile[tx][ty + r];
    }
}

// ---------------- CSR build ----------------
__global__ __launch_bounds__(256) void k_zero(int* __restrict__ p, int n) {
    int i = blockIdx.x * 256 + threadIdx.x;
    if (i < n) p[i] = 0;
}

__global__ void k_hist(const int* __restrict__ ei, int* __restrict__ deg) {
    int e = blockIdx.x * 256 + threadIdx.x;
    if (e >= NE) return;
    atomicAdd(&deg[ei[NE + e]], 1);
}

__global__ __launch_bounds__(256) void k_bsum(const int* __restrict__ deg,
                                              int* __restrict__ bsum) {
    int i = blockIdx.x * 256 + threadIdx.x;
    int v = (i < NN) ? deg[i] : 0;
#pragma unroll
    for (int off = 32; off; off >>= 1) v += __shfl_down(v, off);
    __shared__ int ws[4];
    if ((threadIdx.x & 63) == 0) ws[threadIdx.x >> 6] = v;
    __syncthreads();
    if (threadIdx.x == 0) bsum[blockIdx.x] = ws[0] + ws[1] + ws[2] + ws[3];
}

__global__ __launch_bounds__(256) void k_bscan(const int* __restrict__ bsum,
                                               int* __restrict__ boff) {
    int t = threadIdx.x;
    int orig = (t < SCAN_B) ? bsum[t] : 0;
    int v = orig;
    int lane = t & 63, wid = t >> 6;
#pragma unroll
    for (int off = 1; off < 64; off <<= 1) {
        int u = __shfl_up(v, off);
        if (lane >= off) v += u;
    }
    __shared__ int ws[4];
    if (lane == 63) ws[wid] = v;
    __syncthreads();
    int add = 0;
    for (int wq = 0; wq < wid; ++wq) add += ws[wq];
    if (t < SCAN_B) boff[t] = v + add - orig;  // exclusive
}

__global__ __launch_bounds__(256) void k_scan3(const int* __restrict__ deg,
                                               const int* __restrict__ boff,
                                               int* __restrict__ rowp,
                                               int* __restrict__ cursor) {
    int b = blockIdx.x;
    int i = b * 256 + threadIdx.x;
    int d = (i < NN) ? deg[i] : 0;
    int v = d;
    int lane = threadIdx.x & 63, wid = threadIdx.x >> 6;
#pragma unroll
    for (int off = 1; off < 64; off <<= 1) {
        int u = __shfl_up(v, off);
        if (lane >= off) v += u;
    }
    __shared__ int ws[4];
    if (lane == 63) ws[wid] = v;
    __syncthreads();
    int add = boff[b];
    for (int wq = 0; wq < wid; ++wq) add += ws[wq];
    int excl = add + v - d;
    if (i < NN) { rowp[i] = excl; cursor[i] = excl; }
    if (i == NN - 1) rowp[NN] = excl + d;
}

__global__ void k_scatter(const int* __restrict__ ei, int* __restrict__ cursor,
                          int* __restrict__ colidx) {
    int e = blockIdx.x * 256 + threadIdx.x;
    if (e >= NE) return;
    int s = ei[e], d = ei[NE + e];
    int pos = atomicAdd(&cursor[d], 1);
    colidx[pos] = s;
}

// ---------------- fused GAT aggregation (one wave per dst node), bf16 in/out ----------------
template<int HD>
__global__ __launch_bounds__(256) void gat_agg(const short* __restrict__ hW,
                                               const float* __restrict__ a_s,
                                               const float* __restrict__ a_d,
                                               const int* __restrict__ row_ptr,
                                               const int* __restrict__ colidx,
                                               const float* __restrict__ bias,
                                               short* __restrict__ outp) {
    const int CPL = HD / 64;
    int node = blockIdx.x * 4 + (threadIdx.x >> 6);
    int lane = threadIdx.x & 63;
    if (node >= NN) return;
    int h = lane >> 4;
    int start = row_ptr[node], end = row_ptr[node + 1];
    float adst = a_d[node * 4 + h];
    float eself = lrelu(a_s[node * 4 + h] + adst);

    float z = 1.f;  // exp(eself - eself)
    float acc[CPL];
    {
        const short* row = hW + (size_t)node * HD + lane * CPL;
        if (CPL == 4) { short4 q = *(const short4*)row; acc[0]=b2f(q.x); acc[1]=b2f(q.y); acc[2]=b2f(q.z); acc[3]=b2f(q.w); }
        else          { short2 q = *(const short2*)row; acc[0]=b2f(q.x); acc[1]=b2f(q.y); }
    }
    for (int e = start; e < end; e += 8) {
        int sidx[8];
        float xs[8], ex[8];
#pragma unroll
        for (int q = 0; q < 8; ++q) {
            int ee = e + q;
            sidx[q] = colidx[ee < end ? ee : end - 1];
        }
#pragma unroll
        for (int q = 0; q < 8; ++q) xs[q] = a_s[sidx[q] * 4 + h];
        float v[8][CPL];
        if (CPL == 4) {
#pragma unroll
            for (int q = 0; q < 8; ++q) {
                short4 qq = *(const short4*)(hW + (size_t)sidx[q] * HD + lane * 4);
                v[q][0]=b2f(qq.x); v[q][1]=b2f(qq.y); v[q][2]=b2f(qq.z); v[q][3]=b2f(qq.w);
            }
        } else {
#pragma unroll
            for (int q = 0; q < 8; ++q) {
                short2 qq = *(const short2*)(hW + (size_t)sidx[q] * HD + lane * 2);
                v[q][0]=b2f(qq.x); v[q][1]=b2f(qq.y);
            }
        }
#pragma unroll
        for (int q = 0; q < 8; ++q) {
            float w = __expf(lrelu(xs[q] + adst) - eself);
            ex[q] = (e + q < end) ? w : 0.f;
        }
#pragma unroll
        for (int q = 0; q < 8; ++q) z += ex[q];
#pragma unroll
        for (int j = 0; j < CPL; ++j) {
            float a = 0.f;
#pragma unroll
            for (int q = 0; q < 8; ++q) a += ex[q] * v[q][j];
            acc[j] += a;
        }
    }
    float inv = 1.f / z;
    short* orow = outp + (size_t)node * HD + lane * CPL;
#pragma unroll
    for (int j = 0; j < CPL; ++j)
        orow[j] = f2b(fmaxf(acc[j] * inv + bias[lane * CPL + j], 0.f));
}

// ---------------- pooling + classifier heads ----------------
__global__ __launch_bounds__(512) void pool_head(const short* __restrict__ h2,
                                                 const int* __restrict__ batch,
                                                 const float* __restrict__ W_cls,
                                                 const float* __restrict__ b_cls,
                                                 const float* __restrict__ W_conf,
                                                 const float* __restrict__ b_conf,
                                                 float* __restrict__ out) {
    int b = blockIdx.x;
    int t = threadIdx.x & 127;
    int g = threadIdx.x >> 7;
    int lo = 0, hi = NN;
    while (lo < hi) { int mid = (lo + hi) >> 1; if (batch[mid] < b) lo = mid + 1; else hi = mid; }
    int start = lo;
    lo = 0; hi = NN;
    while (lo < hi) { int mid = (lo + hi) >> 1; if (batch[mid] < b + 1) lo = mid + 1; else hi = mid; }
    int end = lo;

    float acc = 0.f;
    for (int n = start + g; n < end; n += 4) acc += b2f(h2[(size_t)n * 128 + t]);
    __shared__ float se[4][128];
    se[g][t] = acc;
    __syncthreads();
    if (g == 0) {
        float emb = (se[0][t] + se[1][t] + se[2][t] + se[3][t]) /
                    fmaxf((float)(end - start), 1.f);
        se[0][t] = emb;
    }
    __syncthreads();
    if (threadIdx.x == 0) {
        float v = b_cls[0];
        for (int c = 0; c < 128; ++c) v += se[0][c] * W_cls[c * 2 + 0];
        out[b * 2 + 0] = v;
    } else if (threadIdx.x == 1) {
        float v = b_cls[1];
        for (int c = 0; c < 128; ++c) v += se[0][c] * W_cls[c * 2 + 1];
        out[b * 2 + 1] = v;
    } else if (threadIdx.x == 2) {
        float v = b_conf[0];
        for (int c = 0; c < 128; ++c) v += se[0][c] * W_conf[c];
        out[128 + b] = 1.f / (1.f + expf(-v));
    }
}

extern "C" void kernel_launch(void* const* d_in, const int* in_sizes, int n_in,
                              void* d_out, int out_size, void* d_ws, size_t ws_size,
                              hipStream_t stream) {
    const float* x        = (const float*)d_in[0];
    const int*   ei       = (const int*)d_in[1];
    const int*   batch    = (const int*)d_in[2];
    const float* W_in     = (const float*)d_in[3];
    const float* b_in     = (const float*)d_in[4];
    const float* W1       = (const float*)d_in[5];
    const float* att_src1 = (const float*)d_in[6];
    const float* att_dst1 = (const float*)d_in[7];
    const float* b1       = (const float*)d_in[8];
    const float* W2       = (const float*)d_in[9];
    const float* att_src2 = (const float*)d_in[10];
    const float* att_dst2 = (const float*)d_in[11];
    const float* b2       = (const float*)d_in[12];
    const float* W_cls    = (const float*)d_in[13];
    const float* b_cls    = (const float*)d_in[14];
    const float* W_conf   = (const float*)d_in[15];
    const float* b_conf   = (const float*)d_in[16];
    float* out = (float*)d_out;

    char* ws = (char*)d_ws;
    short* h0  = (short*)(ws + 0);            // [MPAD][256] 25,624,576 B
    short* hW1 = (short*)(ws + 25624576);     // [MPAD][256]
    short* h1  = (short*)(ws + 51249152);     // [MPAD][256]
    short* hW2 = (short*)(ws + 76873728);     // [MPAD][128] 12,812,288 B
    short* h2  = (short*)(ws + 89686016);     // [MPAD][128]
    size_t base = 102498304;
    short* Wt_in = (short*)(ws + base);               // [256][800]
    short* Wt1   = (short*)(ws + base + 409600);      // [256][256]
    short* Wt2   = (short*)(ws + base + 540672);      // [128][256]
    float* a_s1  = (float*)(ws + base + 606208);      // [50000][4] (reused layer 2)
    float* a_d1  = (float*)(ws + base + 1406208);
    int*   deg    = (int*)(ws + base + 2206208);
    int*   rowp   = (int*)(ws + base + 2406208);
    int*   cursor = (int*)(ws + base + 2606272);
    int*   colidx = (int*)(ws + base + 2806272);      // [800000]
    int*   bsum   = (int*)(ws + base + 6006272);      // [256]
    int*   boff   = (int*)(ws + base + 6007296);      // [256]

    // weight casts (transpose + K-pad)
    k_wt_t<<<dim3(25, 8), 256, 0, stream>>>(W_in, Wt_in, IND, 256, 800);
    k_wt_t<<<dim3(8, 8), 256, 0, stream>>>(W1, Wt1, 256, 256, 256);
    k_wt_t<<<dim3(8, 4), 256, 0, stream>>>(W2, Wt2, 256, 128, 256);

    // CSR build (hierarchical scan)
    k_zero<<<SCAN_B, 256, 0, stream>>>(deg, NN);
    k_hist<<<NE / 256, 256, 0, stream>>>(ei, deg);
    k_bsum<<<SCAN_B, 256, 0, stream>>>(deg, bsum);
    k_bscan<<<1, 256, 0, stream>>>(bsum, boff);
    k_scan3<<<SCAN_B, 256, 0, stream>>>(deg, boff, rowp, cursor);
    k_scatter<<<NE / 256, 256, 0, stream>>>(ei, cursor, colidx);

    // h0 = relu(x @ W_in + b_in)  (fp32 A read directly, cast fused)
    gemm_a<<<391, 512, 0, stream>>>(x, Wt_in, b_in, h0);
    // hW1 = h0 @ W1, att dots fused
    gemm_b<<<391, 512, 0, stream>>>(h0, Wt1, att_src1, att_dst1, hW1, a_s1, a_d1);
    gat_agg<256><<<12500, 256, 0, stream>>>(hW1, a_s1, a_d1, rowp, colidx, b1, h1);
    // hW2 = h1 @ W2, att dots fused
    gemm_c<<<391, 256, 0, stream>>>(h1, Wt2, att_src2, att_dst2, hW2, a_s1, a_d1);
    gat_agg<128><<<12500, 256, 0, stream>>>(hW2, a_s1, a_d1, rowp, colidx, b2, h2);
    pool_head<<<NB, 512, 0, stream>>>(h2, batch, W_cls, b_cls, W_conf, b_conf, out);
}

// Round 8
// 380.524 us; speedup vs baseline: 1.4992x; 1.0756x over previous
//
#include <hip/hip_runtime.h>
#include <math.h>

#define NN 50000
#define NE 800000
#define NB 64
#define IND 773
#define MPAD 50048   // 128-row-padded M
#define SCAN_B 196   // ceil(NN/256)

typedef __attribute__((ext_vector_type(8))) short short8_t;
typedef __attribute__((ext_vector_type(4))) float f32x4;

__device__ __forceinline__ float lrelu(float x) { return x > 0.f ? x : 0.2f * x; }
__device__ __forceinline__ short f2b(float f) {
    unsigned u = __float_as_uint(f);
    unsigned r = (u + 0x7fffu + ((u >> 16) & 1u)) >> 16;  // RNE
    return (short)r;
}
__device__ __forceinline__ float b2f(short s) {
    return __uint_as_float(((unsigned)(unsigned short)s) << 16);
}

#define GLOAD16(g, l) __builtin_amdgcn_global_load_lds(                         \
    (const __attribute__((address_space(1))) void*)(g),                         \
    (__attribute__((address_space(3))) void*)(l), 16, 0, 0)

// ---------------- GEMM1, fused fp32->bf16 cast, 2-deep pipelined ----------------
// h0 = relu(x @ Wt_in^T + b_in). x fp32 [NN][773]; Wt_in [256][800] bf16.
// 128x256 tile, 512 thr / 8 waves. A: global->reg->LDS (dbuf); B: global_load_lds (dbuf).
__global__ __launch_bounds__(512) void gemm_a(const float* __restrict__ X,
                                              const short* __restrict__ Bt,
                                              const float* __restrict__ bias,
                                              short* __restrict__ C) {
    const int K = 800, N = 256, NT = 25;
    __shared__ short As[2][128 * 32];   // 2 x 8 KB
    __shared__ short Bs[2][256 * 32];   // 2 x 16 KB
    const int t = threadIdx.x;
    const int w = t >> 6, l = t & 63;
    const int l15 = l & 15, lh = l >> 4;
    const int bm = blockIdx.x * 128;
    const int wr = (w >> 2) * 64, wc = (w & 3) * 64;
    const int arow = t >> 2, acb = (t & 3) * 8;   // A-staging: row 0..127, col base
    const int gm = bm + arow;
    const bool rowok = gm < NN;
    const float* xrow = X + (size_t)gm * IND;
    const short* bG = Bt + (size_t)(t >> 2) * K + (t & 3) * 8;

    f32x4 acc[4][4];
#pragma unroll
    for (int i = 0; i < 4; ++i)
#pragma unroll
        for (int j = 0; j < 4; ++j) acc[i][j] = (f32x4){0.f, 0.f, 0.f, 0.f};

    short8_t rA;
    // loadA(it): 8 fp32 -> 8 bf16 in regs
    auto loadA = [&](int it) {
        int gk = it * 32 + acb;
        if (rowok && gk + 7 < IND) {
            float4 v0 = *(const float4*)(xrow + gk);
            float4 v1 = *(const float4*)(xrow + gk + 4);
            rA[0] = f2b(v0.x); rA[1] = f2b(v0.y); rA[2] = f2b(v0.z); rA[3] = f2b(v0.w);
            rA[4] = f2b(v1.x); rA[5] = f2b(v1.y); rA[6] = f2b(v1.z); rA[7] = f2b(v1.w);
        } else {
#pragma unroll
            for (int j = 0; j < 8; ++j)
                rA[j] = (rowok && gk + j < IND) ? f2b(xrow[gk + j]) : (short)0;
        }
    };

    // prologue: fill stage 0 and issue stage 1
    loadA(0);
    GLOAD16(bG, &Bs[0][w * 512]);
    GLOAD16(bG + (size_t)128 * K, &Bs[0][128 * 32 + w * 512]);
    *(short8_t*)&As[0][arow * 32 + acb] = rA;
    loadA(1);
    GLOAD16(bG + 32, &Bs[1][w * 512]);
    GLOAD16(bG + (size_t)128 * K + 32, &Bs[1][128 * 32 + w * 512]);
    __syncthreads();

    for (int it = 0; it < NT; ++it) {
        const int c = it & 1, n = c ^ 1;
        short8_t af[4], bfr[4];
#pragma unroll
        for (int mi = 0; mi < 4; ++mi)
            af[mi] = *(const short8_t*)&As[c][(wr + mi * 16 + l15) * 32 + lh * 8];
#pragma unroll
        for (int ni = 0; ni < 4; ++ni)
            bfr[ni] = *(const short8_t*)&Bs[c][(wc + ni * 16 + l15) * 32 + lh * 8];
        if (it + 1 < NT) *(short8_t*)&As[n][arow * 32 + acb] = rA;  // A(it+1) -> LDS
        if (it + 2 < NT) loadA(it + 2);                              // issue A(it+2) globals
#pragma unroll
        for (int mi = 0; mi < 4; ++mi)
#pragma unroll
            for (int ni = 0; ni < 4; ++ni)
                acc[mi][ni] = __builtin_amdgcn_mfma_f32_16x16x32_bf16(af[mi], bfr[ni], acc[mi][ni], 0, 0, 0);
        __syncthreads();
        if (it + 2 < NT) {  // B(it+2) into just-consumed buffer
            GLOAD16(bG + (it + 2) * 32, &Bs[c][w * 512]);
            GLOAD16(bG + (size_t)128 * K + (it + 2) * 32, &Bs[c][128 * 32 + w * 512]);
        }
    }

#pragma unroll
    for (int mi = 0; mi < 4; ++mi) {
#pragma unroll
        for (int r = 0; r < 4; ++r) {
            int grow = bm + wr + mi * 16 + lh * 4 + r;
            if (grow >= NN) continue;
#pragma unroll
            for (int ni = 0; ni < 4; ++ni) {
                int gcol = wc + ni * 16 + l15;
                float v = fmaxf(acc[mi][ni][r] + bias[gcol], 0.f);
                C[(size_t)grow * N + gcol] = f2b(v);
            }
        }
    }
}

// ---------------- GEMM2 (m97, 256 thr, grid (391,2)) fused att dots (D=64) ----------------
__global__ __launch_bounds__(256) void gemm_b(const short* __restrict__ A,    // h0 [MPAD][256]
                                              const short* __restrict__ Bt,   // Wt1 [256][256]
                                              const float* __restrict__ att_s,
                                              const float* __restrict__ att_d,
                                              short* __restrict__ C,          // hW1
                                              float* __restrict__ a_s,
                                              float* __restrict__ a_d) {
    const int K = 256, N = 256;
    __shared__ short As[128 * 32];
    __shared__ short Bs[128 * 32];
    const int t = threadIdx.x;
    const int w = t >> 6, l = t & 63;
    const int l15 = l & 15, lh = l >> 4;
    const int bm = blockIdx.x * 128, bn = blockIdx.y * 128;
    const int wr = (w >> 1) * 64, wc = (w & 1) * 64;

    const short* aG = A + (size_t)(bm + w * 32 + (l >> 2)) * K + (l & 3) * 8;
    const short* bG = Bt + (size_t)(bn + w * 32 + (l >> 2)) * K + (l & 3) * 8;
    short* aL = As + (w * 32) * 32;
    short* bL = Bs + (w * 32) * 32;

    f32x4 acc[4][4];
#pragma unroll
    for (int i = 0; i < 4; ++i)
#pragma unroll
        for (int j = 0; j < 4; ++j) acc[i][j] = (f32x4){0.f, 0.f, 0.f, 0.f};

    for (int k0 = 0; k0 < K; k0 += 32) {
        __syncthreads();
        GLOAD16(aG + k0, aL);
        GLOAD16(aG + (size_t)16 * K + k0, aL + 16 * 32);
        GLOAD16(bG + k0, bL);
        GLOAD16(bG + (size_t)16 * K + k0, bL + 16 * 32);
        __syncthreads();
        short8_t af[4], bfr[4];
#pragma unroll
        for (int mi = 0; mi < 4; ++mi)
            af[mi] = *(const short8_t*)&As[(wr + mi * 16 + l15) * 32 + lh * 8];
#pragma unroll
        for (int ni = 0; ni < 4; ++ni)
            bfr[ni] = *(const short8_t*)&Bs[(wc + ni * 16 + l15) * 32 + lh * 8];
#pragma unroll
        for (int mi = 0; mi < 4; ++mi)
#pragma unroll
            for (int ni = 0; ni < 4; ++ni)
                acc[mi][ni] = __builtin_amdgcn_mfma_f32_16x16x32_bf16(af[mi], bfr[ni], acc[mi][ni], 0, 0, 0);
    }
    const int head = (bn + wc) >> 6;  // wave's 64 cols = one head
    float sa[4], sd[4];
#pragma unroll
    for (int ni = 0; ni < 4; ++ni) {
        sa[ni] = att_s[head * 64 + ni * 16 + l15];
        sd[ni] = att_d[head * 64 + ni * 16 + l15];
    }
#pragma unroll
    for (int mi = 0; mi < 4; ++mi) {
#pragma unroll
        for (int r = 0; r < 4; ++r) {
            int grow = bm + wr + mi * 16 + lh * 4 + r;
            float s = acc[mi][0][r] * sa[0] + acc[mi][1][r] * sa[1] +
                      acc[mi][2][r] * sa[2] + acc[mi][3][r] * sa[3];
            float d = acc[mi][0][r] * sd[0] + acc[mi][1][r] * sd[1] +
                      acc[mi][2][r] * sd[2] + acc[mi][3][r] * sd[3];
#pragma unroll
            for (int off = 1; off < 16; off <<= 1) {
                s += __shfl_xor(s, off);
                d += __shfl_xor(d, off);
            }
            if (grow < NN) {
                if (l15 == 0) { a_s[grow * 4 + head] = s; a_d[grow * 4 + head] = d; }
#pragma unroll
                for (int ni = 0; ni < 4; ++ni)
                    C[(size_t)grow * N + bn + wc + ni * 16 + l15] = f2b(acc[mi][ni][r]);
            }
        }
    }
}

// ---------------- GEMM3 (m97) fused att dots (D=32) ----------------
__global__ __launch_bounds__(256) void gemm_c(const short* __restrict__ A,    // h1 [MPAD][256]
                                              const short* __restrict__ Bt,   // Wt2 [128][256]
                                              const float* __restrict__ att_s,
                                              const float* __restrict__ att_d,
                                              short* __restrict__ C,          // hW2 [MPAD][128]
                                              float* __restrict__ a_s,
                                              float* __restrict__ a_d) {
    const int K = 256, N = 128;
    __shared__ short As[128 * 32];
    __shared__ short Bs[128 * 32];
    const int t = threadIdx.x;
    const int w = t >> 6, l = t & 63;
    const int l15 = l & 15, lh = l >> 4;
    const int bm = blockIdx.x * 128;
    const int wr = (w >> 1) * 64, wc = (w & 1) * 64;

    const short* aG = A + (size_t)(bm + w * 32 + (l >> 2)) * K + (l & 3) * 8;
    const short* bG = Bt + (size_t)(w * 32 + (l >> 2)) * K + (l & 3) * 8;
    short* aL = As + (w * 32) * 32;
    short* bL = Bs + (w * 32) * 32;

    f32x4 acc[4][4];
#pragma unroll
    for (int i = 0; i < 4; ++i)
#pragma unroll
        for (int j = 0; j < 4; ++j) acc[i][j] = (f32x4){0.f, 0.f, 0.f, 0.f};

    for (int k0 = 0; k0 < K; k0 += 32) {
        __syncthreads();
        GLOAD16(aG + k0, aL);
        GLOAD16(aG + (size_t)16 * K + k0, aL + 16 * 32);
        GLOAD16(bG + k0, bL);
        GLOAD16(bG + (size_t)16 * K + k0, bL + 16 * 32);
        __syncthreads();
        short8_t af[4], bfr[4];
#pragma unroll
        for (int mi = 0; mi < 4; ++mi)
            af[mi] = *(const short8_t*)&As[(wr + mi * 16 + l15) * 32 + lh * 8];
#pragma unroll
        for (int ni = 0; ni < 4; ++ni)
            bfr[ni] = *(const short8_t*)&Bs[(wc + ni * 16 + l15) * 32 + lh * 8];
#pragma unroll
        for (int mi = 0; mi < 4; ++mi)
#pragma unroll
            for (int ni = 0; ni < 4; ++ni)
                acc[mi][ni] = __builtin_amdgcn_mfma_f32_16x16x32_bf16(af[mi], bfr[ni], acc[mi][ni], 0, 0, 0);
    }
    const int h0 = wc >> 5;  // wave = 2 heads of 32 cols
    float sa[4], sd[4];
#pragma unroll
    for (int ni = 0; ni < 4; ++ni) {
        int idx = (h0 + (ni >> 1)) * 32 + (ni & 1) * 16 + l15;
        sa[ni] = att_s[idx];
        sd[ni] = att_d[idx];
    }
#pragma unroll
    for (int mi = 0; mi < 4; ++mi) {
#pragma unroll
        for (int r = 0; r < 4; ++r) {
            int grow = bm + wr + mi * 16 + lh * 4 + r;
            float s0 = acc[mi][0][r] * sa[0] + acc[mi][1][r] * sa[1];
            float s1 = acc[mi][2][r] * sa[2] + acc[mi][3][r] * sa[3];
            float d0 = acc[mi][0][r] * sd[0] + acc[mi][1][r] * sd[1];
            float d1 = acc[mi][2][r] * sd[2] + acc[mi][3][r] * sd[3];
#pragma unroll
            for (int off = 1; off < 16; off <<= 1) {
                s0 += __shfl_xor(s0, off); s1 += __shfl_xor(s1, off);
                d0 += __shfl_xor(d0, off); d1 += __shfl_xor(d1, off);
            }
            if (grow < NN) {
                if (l15 == 0) {
                    a_s[grow * 4 + h0] = s0; a_s[grow * 4 + h0 + 1] = s1;
                    a_d[grow * 4 + h0] = d0; a_d[grow * 4 + h0 + 1] = d1;
                }
#pragma unroll
                for (int ni = 0; ni < 4; ++ni)
                    C[(size_t)grow * N + wc + ni * 16 + l15] = f2b(acc[mi][ni][r]);
            }
        }
    }
}

// ---------------- weight transpose+pad cast via LDS tile ----------------
__global__ __launch_bounds__(256) void k_wt_t(const float* __restrict__ W,
                                              short* __restrict__ Wt,
                                              int K, int N, int Kp) {
    __shared__ short tile[32][33];
    int kb = blockIdx.x * 32, nb = blockIdx.y * 32;
    int tx = threadIdx.x & 31, ty = threadIdx.x >> 5;  // 32 x 8
#pragma unroll
    for (int r = 0; r < 32; r += 8) {
        int k = kb + ty + r;
        tile[ty + r][tx] = (k < K) ? f2b(W[(size_t)k * N + nb + tx]) : (short)0;
    }
    __syncthreads();
#pragma unroll
    for (int r = 0; r < 32; r += 8) {
        int n = nb + ty + r, k = kb + tx;
        Wt[(size_t)n * Kp + k] = tile[tx][ty + r];
    }
}

// ---------------- CSR build ----------------
__global__ __launch_bounds__(256) void k_zero(int* __restrict__ p, int n) {
    int i = blockIdx.x * 256 + threadIdx.x;
    if (i < n) p[i] = 0;
}

__global__ void k_hist(const int* __restrict__ ei, int* __restrict__ deg) {
    int e = blockIdx.x * 256 + threadIdx.x;
    if (e >= NE) return;
    atomicAdd(&deg[ei[NE + e]], 1);
}

__global__ __launch_bounds__(256) void k_bsum(const int* __restrict__ deg,
                                              int* __restrict__ bsum) {
    int i = blockIdx.x * 256 + threadIdx.x;
    int v = (i < NN) ? deg[i] : 0;
#pragma unroll
    for (int off = 32; off; off >>= 1) v += __shfl_down(v, off);
    __shared__ int ws[4];
    if ((threadIdx.x & 63) == 0) ws[threadIdx.x >> 6] = v;
    __syncthreads();
    if (threadIdx.x == 0) bsum[blockIdx.x] = ws[0] + ws[1] + ws[2] + ws[3];
}

__global__ __launch_bounds__(256) void k_bscan(const int* __restrict__ bsum,
                                               int* __restrict__ boff) {
    int t = threadIdx.x;
    int orig = (t < SCAN_B) ? bsum[t] : 0;
    int v = orig;
    int lane = t & 63, wid = t >> 6;
#pragma unroll
    for (int off = 1; off < 64; off <<= 1) {
        int u = __shfl_up(v, off);
        if (lane >= off) v += u;
    }
    __shared__ int ws[4];
    if (lane == 63) ws[wid] = v;
    __syncthreads();
    int add = 0;
    for (int wq = 0; wq < wid; ++wq) add += ws[wq];
    if (t < SCAN_B) boff[t] = v + add - orig;  // exclusive
}

__global__ __launch_bounds__(256) void k_scan3(const int* __restrict__ deg,
                                               const int* __restrict__ boff,
                                               int* __restrict__ rowp,
                                               int* __restrict__ cursor) {
    int b = blockIdx.x;
    int i = b * 256 + threadIdx.x;
    int d = (i < NN) ? deg[i] : 0;
    int v = d;
    int lane = threadIdx.x & 63, wid = threadIdx.x >> 6;
#pragma unroll
    for (int off = 1; off < 64; off <<= 1) {
        int u = __shfl_up(v, off);
        if (lane >= off) v += u;
    }
    __shared__ int ws[4];
    if (lane == 63) ws[wid] = v;
    __syncthreads();
    int add = boff[b];
    for (int wq = 0; wq < wid; ++wq) add += ws[wq];
    int excl = add + v - d;
    if (i < NN) { rowp[i] = excl; cursor[i] = excl; }
    if (i == NN - 1) rowp[NN] = excl + d;
}

__global__ void k_scatter(const int* __restrict__ ei, int* __restrict__ cursor,
                          int* __restrict__ colidx) {
    int e = blockIdx.x * 256 + threadIdx.x;
    if (e >= NE) return;
    int s = ei[e], d = ei[NE + e];
    int pos = atomicAdd(&cursor[d], 1);
    colidx[pos] = s;
}

// ---------------- fused GAT aggregation (one wave per dst node), bf16 in/out ----------------
template<int HD>
__global__ __launch_bounds__(256) void gat_agg(const short* __restrict__ hW,
                                               const float* __restrict__ a_s,
                                               const float* __restrict__ a_d,
                                               const int* __restrict__ row_ptr,
                                               const int* __restrict__ colidx,
                                               const float* __restrict__ bias,
                                               short* __restrict__ outp) {
    const int CPL = HD / 64;
    int node = blockIdx.x * 4 + (threadIdx.x >> 6);
    int lane = threadIdx.x & 63;
    if (node >= NN) return;
    int h = lane >> 4;
    int start = row_ptr[node], end = row_ptr[node + 1];
    float adst = a_d[node * 4 + h];
    float eself = lrelu(a_s[node * 4 + h] + adst);

    float z = 1.f;  // exp(eself - eself)
    float acc[CPL];
    {
        const short* row = hW + (size_t)node * HD + lane * CPL;
        if (CPL == 4) { short4 q = *(const short4*)row; acc[0]=b2f(q.x); acc[1]=b2f(q.y); acc[2]=b2f(q.z); acc[3]=b2f(q.w); }
        else          { short2 q = *(const short2*)row; acc[0]=b2f(q.x); acc[1]=b2f(q.y); }
    }
    for (int e = start; e < end; e += 8) {
        int sidx[8];
        float xs[8], ex[8];
#pragma unroll
        for (int q = 0; q < 8; ++q) {
            int ee = e + q;
            sidx[q] = colidx[ee < end ? ee : end - 1];
        }
#pragma unroll
        for (int q = 0; q < 8; ++q) xs[q] = a_s[sidx[q] * 4 + h];
        float v[8][CPL];
        if (CPL == 4) {
#pragma unroll
            for (int q = 0; q < 8; ++q) {
                short4 qq = *(const short4*)(hW + (size_t)sidx[q] * HD + lane * 4);
                v[q][0]=b2f(qq.x); v[q][1]=b2f(qq.y); v[q][2]=b2f(qq.z); v[q][3]=b2f(qq.w);
            }
        } else {
#pragma unroll
            for (int q = 0; q < 8; ++q) {
                short2 qq = *(const short2*)(hW + (size_t)sidx[q] * HD + lane * 2);
                v[q][0]=b2f(qq.x); v[q][1]=b2f(qq.y);
            }
        }
#pragma unroll
        for (int q = 0; q < 8; ++q) {
            float w = __expf(lrelu(xs[q] + adst) - eself);
            ex[q] = (e + q < end) ? w : 0.f;
        }
#pragma unroll
        for (int q = 0; q < 8; ++q) z += ex[q];
#pragma unroll
        for (int j = 0; j < CPL; ++j) {
            float a = 0.f;
#pragma unroll
            for (int q = 0; q < 8; ++q) a += ex[q] * v[q][j];
            acc[j] += a;
        }
    }
    float inv = 1.f / z;
    short* orow = outp + (size_t)node * HD + lane * CPL;
#pragma unroll
    for (int j = 0; j < CPL; ++j)
        orow[j] = f2b(fmaxf(acc[j] * inv + bias[lane * CPL + j], 0.f));
}

// ---------------- pooling + classifier heads ----------------
__global__ __launch_bounds__(512) void pool_head(const short* __restrict__ h2,
                                                 const int* __restrict__ batch,
                                                 const float* __restrict__ W_cls,
                                                 const float* __restrict__ b_cls,
                                                 const float* __restrict__ W_conf,
                                                 const float* __restrict__ b_conf,
                                                 float* __restrict__ out) {
    int b = blockIdx.x;
    int t = threadIdx.x & 127;
    int g = threadIdx.x >> 7;
    int lo = 0, hi = NN;
    while (lo < hi) { int mid = (lo + hi) >> 1; if (batch[mid] < b) lo = mid + 1; else hi = mid; }
    int start = lo;
    lo = 0; hi = NN;
    while (lo < hi) { int mid = (lo + hi) >> 1; if (batch[mid] < b + 1) lo = mid + 1; else hi = mid; }
    int end = lo;

    float acc = 0.f;
    for (int n = start + g; n < end; n += 4) acc += b2f(h2[(size_t)n * 128 + t]);
    __shared__ float se[4][128];
    se[g][t] = acc;
    __syncthreads();
    if (g == 0) {
        float emb = (se[0][t] + se[1][t] + se[2][t] + se[3][t]) /
                    fmaxf((float)(end - start), 1.f);
        se[0][t] = emb;
    }
    __syncthreads();
    if (threadIdx.x == 0) {
        float v = b_cls[0];
        for (int c = 0; c < 128; ++c) v += se[0][c] * W_cls[c * 2 + 0];
        out[b * 2 + 0] = v;
    } else if (threadIdx.x == 1) {
        float v = b_cls[1];
        for (int c = 0; c < 128; ++c) v += se[0][c] * W_cls[c * 2 + 1];
        out[b * 2 + 1] = v;
    } else if (threadIdx.x == 2) {
        float v = b_conf[0];
        for (int c = 0; c < 128; ++c) v += se[0][c] * W_conf[c];
        out[128 + b] = 1.f / (1.f + expf(-v));
    }
}

extern "C" void kernel_launch(void* const* d_in, const int* in_sizes, int n_in,
                              void* d_out, int out_size, void* d_ws, size_t ws_size,
                              hipStream_t stream) {
    const float* x        = (const float*)d_in[0];
    const int*   ei       = (const int*)d_in[1];
    const int*   batch    = (const int*)d_in[2];
    const float* W_in     = (const float*)d_in[3];
    const float* b_in     = (const float*)d_in[4];
    const float* W1       = (const float*)d_in[5];
    const float* att_src1 = (const float*)d_in[6];
    const float* att_dst1 = (const float*)d_in[7];
    const float* b1       = (const float*)d_in[8];
    const float* W2       = (const float*)d_in[9];
    const float* att_src2 = (const float*)d_in[10];
    const float* att_dst2 = (const float*)d_in[11];
    const float* b2       = (const float*)d_in[12];
    const float* W_cls    = (const float*)d_in[13];
    const float* b_cls    = (const float*)d_in[14];
    const float* W_conf   = (const float*)d_in[15];
    const float* b_conf   = (const float*)d_in[16];
    float* out = (float*)d_out;

    char* ws = (char*)d_ws;
    short* h0  = (short*)(ws + 0);            // [MPAD][256]
    short* hW1 = (short*)(ws + 25624576);     // [MPAD][256]
    short* h1  = (short*)(ws + 51249152);     // [MPAD][256]
    short* hW2 = (short*)(ws + 76873728);     // [MPAD][128]
    short* h2  = (short*)(ws + 89686016);     // [MPAD][128]
    size_t base = 102498304;
    short* Wt_in = (short*)(ws + base);               // [256][800]
    short* Wt1   = (short*)(ws + base + 409600);      // [256][256]
    short* Wt2   = (short*)(ws + base + 540672);      // [128][256]
    float* a_s1  = (float*)(ws + base + 606208);      // [50000][4] (reused layer 2)
    float* a_d1  = (float*)(ws + base + 1406208);
    int*   deg    = (int*)(ws + base + 2206208);
    int*   rowp   = (int*)(ws + base + 2406208);
    int*   cursor = (int*)(ws + base + 2606272);
    int*   colidx = (int*)(ws + base + 2806272);      // [800000]
    int*   bsum   = (int*)(ws + base + 6006272);      // [256]
    int*   boff   = (int*)(ws + base + 6007296);      // [256]

    // weight casts (transpose + K-pad)
    k_wt_t<<<dim3(25, 8), 256, 0, stream>>>(W_in, Wt_in, IND, 256, 800);
    k_wt_t<<<dim3(8, 8), 256, 0, stream>>>(W1, Wt1, 256, 256, 256);
    k_wt_t<<<dim3(8, 4), 256, 0, stream>>>(W2, Wt2, 256, 128, 256);

    // CSR build (hierarchical scan)
    k_zero<<<SCAN_B, 256, 0, stream>>>(deg, NN);
    k_hist<<<NE / 256, 256, 0, stream>>>(ei, deg);
    k_bsum<<<SCAN_B, 256, 0, stream>>>(deg, bsum);
    k_bscan<<<1, 256, 0, stream>>>(bsum, boff);
    k_scan3<<<SCAN_B, 256, 0, stream>>>(deg, boff, rowp, cursor);
    k_scatter<<<NE / 256, 256, 0, stream>>>(ei, cursor, colidx);

    // h0 = relu(x @ W_in + b_in)  (fp32 A, cast fused, 2-deep pipeline)
    gemm_a<<<391, 512, 0, stream>>>(x, Wt_in, b_in, h0);
    // hW1 = h0 @ W1, att dots fused
    gemm_b<<<dim3(391, 2), 256, 0, stream>>>(h0, Wt1, att_src1, att_dst1, hW1, a_s1, a_d1);
    gat_agg<256><<<12500, 256, 0, stream>>>(hW1, a_s1, a_d1, rowp, colidx, b1, h1);
    // hW2 = h1 @ W2, att dots fused
    gemm_c<<<391, 256, 0, stream>>>(h1, Wt2, att_src2, att_dst2, hW2, a_s1, a_d1);
    gat_agg<128><<<12500, 256, 0, stream>>>(hW2, a_s1, a_d1, rowp, colidx, b2, h2);
    pool_head<<<NB, 512, 0, stream>>>(h2, batch, W_cls, b_cls, W_conf, b_conf, out);
}